// Round 7
// baseline (418.729 us; speedup 1.0000x reference)
//
#include <hip/hip_runtime.h>
#include <hip/hip_bf16.h>
#include <math.h>

using bf16 = __hip_bfloat16;
typedef __attribute__((ext_vector_type(4))) float f32x4;
typedef __attribute__((ext_vector_type(8))) short s16x8;

#define MFMA16(a,b,c) __builtin_amdgcn_mfma_f32_16x16x32_bf16((a),(b),(c),0,0,0)

// ---------------------------------------------------------------------------
// VQ-VAE forward. B=128, L=4096, H=128, RH=64, D=64, K=512.
// Channel-last bf16 activations. Fused enc1+enc2; fused res-blocks;
// fused pre_vq+VQ with register-resident z (no LDS transpose).
// ---------------------------------------------------------------------------

__device__ inline float bf2f(unsigned short u) {
    union { float f; unsigned v; } c; c.v = ((unsigned)u) << 16; return c.f;
}
__device__ inline unsigned short bfbits(float f) {
    union { bf16 h; unsigned short u; } c; c.h = __float2bfloat16(f); return c.u;
}
__device__ inline s16x8 relu8(s16x8 v) {
#pragma unroll
    for (int j = 0; j < 8; ++j)
        v[j] = (short)(((unsigned short)v[j] & 0x8000u) ? 0 : (unsigned short)v[j]);
    return v;
}

enum { M_S1 = 0, M_S2 = 1, M_CT = 2 };

// Generic GEMM-conv (used for enc3, dec1, ct1).
template<int CIN, int COUT, int NTAP, int MODE, bool RELU_IN, bool RELU_OUT,
         bool HAS_BIAS>
__global__ __launch_bounds__(256) void gconv_k(
    const bf16* __restrict__ in, const bf16* __restrict__ wt,
    const float* __restrict__ bias, bf16* __restrict__ out,
    int Lin, int Lout)
{
    constexpr int T  = (MODE == M_S2) ? 132 : ((MODE == M_CT) ? 66 : (NTAP == 3 ? 66 : 64));
    constexpr int NG = (MODE == M_CT) ? 2 : 1;
    constexpr int WL = (COUT == 128) ? 4 : 2;
    constexpr int KS = CIN / 32;
    constexpr int SOFF = (MODE == M_CT || NTAP == 3) ? -1 : 0;
    __shared__ bf16 sX[T * CIN];

    const int tid = threadIdx.x;
    const int b   = blockIdx.y;
    const int l0  = blockIdx.x * 64;
    const bf16* inb = in + (size_t)b * Lin * CIN;

    constexpr int CPR = CIN / 8;
    for (int i = tid; i < T * CPR; i += 256) {
        int t  = i / CPR;
        int c0 = (i - t * CPR) * 8;
        int g;
        if (MODE == M_S2) g = (t < 66) ? 2 * (l0 + t) : 2 * (l0 + t - 66) - 1;
        else              g = l0 + t + SOFF;
        s16x8 v = {};
        if (g >= 0 && g < Lin) v = *(const s16x8*)(inb + (size_t)g * CIN + c0);
        if (RELU_IN) v = relu8(v);
        int byte = ((t * CIN + c0) << 1) ^ ((t & 7) << 4);
        *(s16x8*)((char*)sX + byte) = v;
    }
    __syncthreads();

    const int lane = tid & 63;
    const int wid  = __builtin_amdgcn_readfirstlane(tid >> 6);
    const int co0  = (COUT == 128) ? wid * 32 : (wid & 1) * 32;
    const int lw0  = (COUT == 128) ? 0 : (wid >> 1) * 32;
    const int lr   = lane & 15;
    const int kg   = lane >> 4;

    f32x4 acc[NG][2][WL];
#pragma unroll
    for (int g = 0; g < NG; ++g)
#pragma unroll
        for (int cf = 0; cf < 2; ++cf)
#pragma unroll
            for (int lf = 0; lf < WL; ++lf)
                acc[g][cf][lf] = (f32x4){0.f, 0.f, 0.f, 0.f};

#pragma unroll
    for (int g = 0; g < NG; ++g) {
#pragma unroll
        for (int k = 0; k < NTAP; ++k) {
            int roff;
            if (MODE == M_S1)      roff = k;
            else if (MODE == M_S2) roff = (k == 0) ? 66 : (k == 1) ? 0 : (k == 2) ? 67 : 1;
            else                   roff = g + k;
            const bf16* Ab = wt + (size_t)(g * NTAP + k) * COUT * CIN;
#pragma unroll
            for (int ks = 0; ks < KS; ++ks) {
                s16x8 af[2];
#pragma unroll
                for (int cf = 0; cf < 2; ++cf)
                    af[cf] = *(const s16x8*)(Ab + (co0 + cf * 16 + lr) * CIN + ks * 32 + kg * 8);
                s16x8 bfr[WL];
#pragma unroll
                for (int lf = 0; lf < WL; ++lf) {
                    int t = roff + lw0 + lf * 16 + lr;
                    int byte = ((t * CIN + ks * 32 + kg * 8) << 1) ^ ((t & 7) << 4);
                    bfr[lf] = *(const s16x8*)((const char*)sX + byte);
                }
#pragma unroll
                for (int cf = 0; cf < 2; ++cf)
#pragma unroll
                    for (int lf = 0; lf < WL; ++lf)
                        acc[g][cf][lf] = MFMA16(af[cf], bfr[lf], acc[g][cf][lf]);
            }
        }
    }

#pragma unroll
    for (int g = 0; g < NG; ++g)
#pragma unroll
        for (int cf = 0; cf < 2; ++cf)
#pragma unroll
            for (int lf = 0; lf < WL; ++lf) {
                int cb0  = co0 + cf * 16 + kg * 4;
                int lcol = lw0 + lf * 16 + lr;
                int gcol = (MODE == M_CT) ? (2 * (l0 + lcol) + g) : (l0 + lcol);
                float r[4];
#pragma unroll
                for (int j = 0; j < 4; ++j) {
                    r[j] = acc[g][cf][lf][j];
                    if (HAS_BIAS) r[j] += bias[cb0 + j];
                    if (RELU_OUT) r[j] = fmaxf(r[j], 0.f);
                }
                bf16* po = out + ((size_t)b * Lout + gcol) * COUT + cb0;
                uint2 pk;
                pk.x = (unsigned)bfbits(r[0]) | ((unsigned)bfbits(r[1]) << 16);
                pk.y = (unsigned)bfbits(r[2]) | ((unsigned)bfbits(r[3]) << 16);
                *(uint2*)po = pk;
            }
}

// Fused residual block: x + W2 * relu(W1 * relu(x)) [, relu at stack end].
template<bool RELU_OUT>
__global__ __launch_bounds__(256) void fres_k(
    const bf16* __restrict__ in, const bf16* __restrict__ w1t,
    const bf16* __restrict__ w2t, bf16* __restrict__ out)
{
    __shared__ bf16 sX[66 * 128];
    __shared__ bf16 sH[64 * 64];
    const int tid = threadIdx.x;
    const int b   = blockIdx.y;
    const int l0  = blockIdx.x * 64;
    const bf16* inb = in + (size_t)b * 1024 * 128;

    for (int i = tid; i < 66 * 16; i += 256) {
        int t = i >> 4, c0 = (i & 15) * 8;
        int g = l0 + t - 1;
        s16x8 v = {};
        if (g >= 0 && g < 1024) v = *(const s16x8*)(inb + (size_t)g * 128 + c0);
        int byte = ((t * 128 + c0) << 1) ^ ((t & 7) << 4);
        *(s16x8*)((char*)sX + byte) = v;
    }
    __syncthreads();

    const int lane = tid & 63;
    const int wid  = __builtin_amdgcn_readfirstlane(tid >> 6);
    const int lr   = lane & 15;
    const int kg   = lane >> 4;

    {
        const int co0 = (wid & 1) * 32;
        const int lw0 = (wid >> 1) * 32;
        f32x4 acc[2][2];
#pragma unroll
        for (int cf = 0; cf < 2; ++cf)
#pragma unroll
            for (int lf = 0; lf < 2; ++lf) acc[cf][lf] = (f32x4){0.f, 0.f, 0.f, 0.f};
#pragma unroll
        for (int k = 0; k < 3; ++k) {
            const bf16* Ab = w1t + (size_t)k * 64 * 128;
#pragma unroll
            for (int ks = 0; ks < 4; ++ks) {
                s16x8 af[2];
#pragma unroll
                for (int cf = 0; cf < 2; ++cf)
                    af[cf] = *(const s16x8*)(Ab + (co0 + cf * 16 + lr) * 128 + ks * 32 + kg * 8);
                s16x8 bfr[2];
#pragma unroll
                for (int lf = 0; lf < 2; ++lf) {
                    int t = k + lw0 + lf * 16 + lr;
                    int byte = ((t * 128 + ks * 32 + kg * 8) << 1) ^ ((t & 7) << 4);
                    bfr[lf] = relu8(*(const s16x8*)((const char*)sX + byte));
                }
#pragma unroll
                for (int cf = 0; cf < 2; ++cf)
#pragma unroll
                    for (int lf = 0; lf < 2; ++lf)
                        acc[cf][lf] = MFMA16(af[cf], bfr[lf], acc[cf][lf]);
            }
        }
#pragma unroll
        for (int cf = 0; cf < 2; ++cf)
#pragma unroll
            for (int lf = 0; lf < 2; ++lf) {
                int pos = lw0 + lf * 16 + lr;
                int ch  = co0 + cf * 16 + kg * 4;
                uint2 pk;
                pk.x = (unsigned)bfbits(fmaxf(acc[cf][lf][0], 0.f)) |
                       ((unsigned)bfbits(fmaxf(acc[cf][lf][1], 0.f)) << 16);
                pk.y = (unsigned)bfbits(fmaxf(acc[cf][lf][2], 0.f)) |
                       ((unsigned)bfbits(fmaxf(acc[cf][lf][3], 0.f)) << 16);
                int byte = ((pos * 64 + ch) << 1) ^ ((pos & 7) << 4);
                *(uint2*)((char*)sH + byte) = pk;
            }
    }
    __syncthreads();

    {
        const int co0 = wid * 32;
        f32x4 acc2[2][4];
#pragma unroll
        for (int cf = 0; cf < 2; ++cf)
#pragma unroll
            for (int lf = 0; lf < 4; ++lf) acc2[cf][lf] = (f32x4){0.f, 0.f, 0.f, 0.f};
#pragma unroll
        for (int ks = 0; ks < 2; ++ks) {
            s16x8 af[2];
#pragma unroll
            for (int cf = 0; cf < 2; ++cf)
                af[cf] = *(const s16x8*)(w2t + (size_t)(co0 + cf * 16 + lr) * 64 + ks * 32 + kg * 8);
            s16x8 bfr[4];
#pragma unroll
            for (int lf = 0; lf < 4; ++lf) {
                int t = lf * 16 + lr;
                int byte = ((t * 64 + ks * 32 + kg * 8) << 1) ^ ((t & 7) << 4);
                bfr[lf] = *(const s16x8*)((const char*)sH + byte);
            }
#pragma unroll
            for (int cf = 0; cf < 2; ++cf)
#pragma unroll
                for (int lf = 0; lf < 4; ++lf)
                    acc2[cf][lf] = MFMA16(af[cf], bfr[lf], acc2[cf][lf]);
        }
#pragma unroll
        for (int cf = 0; cf < 2; ++cf)
#pragma unroll
            for (int lf = 0; lf < 4; ++lf) {
                int cb0  = co0 + cf * 16 + kg * 4;
                int lcol = lf * 16 + lr;
                int tX   = lcol + 1;
                int rbyte = ((tX * 128 + cb0) << 1) ^ ((tX & 7) << 4);
                uint2 old = *(const uint2*)((const char*)sX + rbyte);
                float r[4];
                r[0] = acc2[cf][lf][0] + bf2f((unsigned short)(old.x & 0xffff));
                r[1] = acc2[cf][lf][1] + bf2f((unsigned short)(old.x >> 16));
                r[2] = acc2[cf][lf][2] + bf2f((unsigned short)(old.y & 0xffff));
                r[3] = acc2[cf][lf][3] + bf2f((unsigned short)(old.y >> 16));
                if (RELU_OUT)
#pragma unroll
                    for (int j = 0; j < 4; ++j) r[j] = fmaxf(r[j], 0.f);
                uint2 pk;
                pk.x = (unsigned)bfbits(r[0]) | ((unsigned)bfbits(r[1]) << 16);
                pk.y = (unsigned)bfbits(r[2]) | ((unsigned)bfbits(r[3]) << 16);
                *(uint2*)(out + ((size_t)b * 1024 + l0 + lcol) * 128 + cb0) = pk;
            }
    }
}

// Fused enc1+enc2: x fp32 -> h1 (LDS) -> enc2 GEMM -> (b,1024,128) bf16 relu.
__global__ __launch_bounds__(256) void enc12_k(
    const float* __restrict__ x, const float* __restrict__ w1,
    const float* __restrict__ b1, const bf16* __restrict__ w2t,
    const float* __restrict__ b2, bf16* __restrict__ out)
{
    __shared__ float sXf[268];
    __shared__ float sW1[256];
    __shared__ float sB1[64];
    __shared__ bf16 sX[132 * 64];
    const int tid = threadIdx.x;
    const int b   = blockIdx.y;
    const int l0  = blockIdx.x * 64;
    const float* xb = x + (size_t)b * 4096;

    for (int i = tid; i < 266; i += 256) {
        int g = 4 * l0 - 3 + i;
        sXf[i] = (g >= 0 && g < 4096) ? xb[g] : 0.f;
    }
    if (tid < 256) sW1[tid] = w1[tid];
    if (tid < 64)  sB1[tid] = b1[tid];
    __syncthreads();

    // h1 tile: rows 0..65 even (h1[2(l0+t)]), rows 66..131 odd (h1[2(l0+t-66)-1])
    for (int i = tid; i < 132 * 64; i += 256) {
        int t = i >> 6, c = i & 63;
        int p = (t < 66) ? 2 * (l0 + t) : 2 * (l0 + t - 66) - 1;
        float v = 0.f;
        if (p >= 0 && p < 2048) {
            int xi = 2 * p - 4 * l0 + 2;          // (2p-1) - (4l0-3)
            float a = sB1[c];
#pragma unroll
            for (int k = 0; k < 4; ++k) a = fmaf(sXf[xi + k], sW1[c * 4 + k], a);
            v = fmaxf(a, 0.f);
        }
        int byte = ((t * 64 + c) << 1) ^ ((t & 7) << 4);
        *(bf16*)((char*)sX + byte) = __float2bfloat16(v);
    }
    __syncthreads();

    // enc2 GEMM: CIN=64, COUT=128, M_S2 roffs
    const int lane = tid & 63;
    const int wid  = __builtin_amdgcn_readfirstlane(tid >> 6);
    const int co0  = wid * 32;
    const int lr   = lane & 15;
    const int kg   = lane >> 4;

    f32x4 acc[2][4];
#pragma unroll
    for (int cf = 0; cf < 2; ++cf)
#pragma unroll
        for (int lf = 0; lf < 4; ++lf) acc[cf][lf] = (f32x4){0.f, 0.f, 0.f, 0.f};

#pragma unroll
    for (int k = 0; k < 4; ++k) {
        const int roff = (k == 0) ? 66 : (k == 1) ? 0 : (k == 2) ? 67 : 1;
        const bf16* Ab = w2t + (size_t)k * 128 * 64;
#pragma unroll
        for (int ks = 0; ks < 2; ++ks) {
            s16x8 af[2];
#pragma unroll
            for (int cf = 0; cf < 2; ++cf)
                af[cf] = *(const s16x8*)(Ab + (co0 + cf * 16 + lr) * 64 + ks * 32 + kg * 8);
            s16x8 bfr[4];
#pragma unroll
            for (int lf = 0; lf < 4; ++lf) {
                int t = roff + lf * 16 + lr;
                int byte = ((t * 64 + ks * 32 + kg * 8) << 1) ^ ((t & 7) << 4);
                bfr[lf] = *(const s16x8*)((const char*)sX + byte);
            }
#pragma unroll
            for (int cf = 0; cf < 2; ++cf)
#pragma unroll
                for (int lf = 0; lf < 4; ++lf)
                    acc[cf][lf] = MFMA16(af[cf], bfr[lf], acc[cf][lf]);
        }
    }

#pragma unroll
    for (int cf = 0; cf < 2; ++cf)
#pragma unroll
        for (int lf = 0; lf < 4; ++lf) {
            int cb0  = co0 + cf * 16 + kg * 4;
            int lcol = lf * 16 + lr;
            float r[4];
#pragma unroll
            for (int j = 0; j < 4; ++j)
                r[j] = fmaxf(acc[cf][lf][j] + b2[cb0 + j], 0.f);
            uint2 pk;
            pk.x = (unsigned)bfbits(r[0]) | ((unsigned)bfbits(r[1]) << 16);
            pk.y = (unsigned)bfbits(r[2]) | ((unsigned)bfbits(r[3]) << 16);
            *(uint2*)(out + ((size_t)b * 1024 + l0 + lcol) * 128 + cb0) = pk;
        }
}

// Final convT: 64->1 ch, x2 upsample; (b,l,c) bf16 in, fp32 out.
__global__ __launch_bounds__(256) void ct2_k(
    const bf16* __restrict__ in, const float* __restrict__ w,
    const float* __restrict__ bias, float* __restrict__ out)
{
    __shared__ bf16 sX[258 * 64];
    const int tid = threadIdx.x;
    const int b   = blockIdx.y;
    const int m0  = blockIdx.x * 256;
    const bf16* inb = in + (size_t)b * 2048 * 64;
    for (int i = tid; i < 258 * 8; i += 256) {
        int t = i >> 3, c0 = (i & 7) * 8;
        int g = m0 - 1 + t;
        s16x8 v = {};
        if (g >= 0 && g < 2048) v = *(const s16x8*)(inb + (size_t)g * 64 + c0);
        int byte = ((t * 64 + c0) << 1) ^ ((t & 7) << 4);
        *(s16x8*)((char*)sX + byte) = v;
    }
    __syncthreads();
    float e = bias[0], o = bias[0];
#pragma unroll
    for (int c0 = 0; c0 < 64; c0 += 8) {
        int t0 = tid, t1 = tid + 1, t2 = tid + 2;
        s16x8 vm1 = *(const s16x8*)((char*)sX + (((t0 * 64 + c0) << 1) ^ ((t0 & 7) << 4)));
        s16x8 v0  = *(const s16x8*)((char*)sX + (((t1 * 64 + c0) << 1) ^ ((t1 & 7) << 4)));
        s16x8 vp1 = *(const s16x8*)((char*)sX + (((t2 * 64 + c0) << 1) ^ ((t2 & 7) << 4)));
#pragma unroll
        for (int j = 0; j < 8; ++j) {
            int ci = c0 + j;
            float xm1 = bf2f((unsigned short)vm1[j]);
            float x0  = bf2f((unsigned short)v0[j]);
            float xp1 = bf2f((unsigned short)vp1[j]);
            e = fmaf(x0,  w[ci * 4 + 1], fmaf(xm1, w[ci * 4 + 3], e));
            o = fmaf(xp1, w[ci * 4 + 0], fmaf(x0,  w[ci * 4 + 2], o));
        }
    }
    int m = m0 + tid;
    out[(size_t)b * 4096 + 2 * m]     = e;
    out[(size_t)b * 4096 + 2 * m + 1] = o;
}

// Weight transform: fp32 conv weights -> bf16 [tap][co][ci] matrices.
__global__ __launch_bounds__(256) void wx_k(
    const float* ew2, const float* ew3, const float* er1a, const float* er1b,
    const float* er2a, const float* er2b, const float* pvw, const float* dw1,
    const float* dr1a, const float* dr1b, const float* dr2a, const float* dr2b,
    const float* ct1w, bf16* wb)
{
    const int job = blockIdx.x;
    bf16* dst = wb + (size_t)job * 65536;
    const float* src; int CO, CI, K;
    switch (job) {
        case 0:  src = ew2;  CO = 128; CI = 64;  K = 4; break;
        case 1:  src = ew3;  CO = 128; CI = 128; K = 3; break;
        case 2:  src = er1a; CO = 64;  CI = 128; K = 3; break;
        case 3:  src = er1b; CO = 128; CI = 64;  K = 1; break;
        case 4:  src = er2a; CO = 64;  CI = 128; K = 3; break;
        case 5:  src = er2b; CO = 128; CI = 64;  K = 1; break;
        case 6:  src = pvw;  CO = 64;  CI = 128; K = 1; break;
        case 7:  src = dw1;  CO = 128; CI = 64;  K = 3; break;
        case 8:  src = dr1a; CO = 64;  CI = 128; K = 3; break;
        case 9:  src = dr1b; CO = 128; CI = 64;  K = 1; break;
        case 10: src = dr2a; CO = 64;  CI = 128; K = 3; break;
        case 11: src = dr2b; CO = 128; CI = 64;  K = 1; break;
        default: src = ct1w; CO = 64;  CI = 128; K = 4; break;
    }
    const int tot = CO * CI * K;
    for (int i = blockIdx.y * 256 + threadIdx.x; i < tot; i += gridDim.y * 256) {
        if (job < 12) {
            int k = i / (CO * CI); int r = i - k * CO * CI;
            int co = r / CI; int ci = r - co * CI;
            dst[i] = __float2bfloat16(src[((size_t)co * CI + ci) * K + k]);
        } else {
            const int TAP[4] = {3, 1, 2, 0};   // [We0,We1,Wo0,Wo1]
            int g = i / (64 * 128); int r = i - g * 64 * 128;
            int co = r / 128; int ci = r - co * 128;
            dst[i] = __float2bfloat16(src[((size_t)ci * 64 + co) * 4 + TAP[g]]);
        }
    }
}

// codebook prep: fp32 norms + hi bf16
__global__ __launch_bounds__(256) void cbprep_k(
    const float* __restrict__ cb, bf16* __restrict__ cbh, float* __restrict__ sc)
{
    int k = blockIdx.x * 256 + threadIdx.x;   // grid 2
    const float* c = cb + (size_t)k * 64;
    float s = 0.f;
#pragma unroll
    for (int d = 0; d < 64; ++d) s = fmaf(c[d], c[d], s);
    sc[k] = s;
#pragma unroll
    for (int c0 = 0; c0 < 64; c0 += 8) {
        union { unsigned short u[8]; s16x8 v; } ph;
#pragma unroll
        for (int j = 0; j < 8; ++j) ph.u[j] = bfbits(c[c0 + j]);
        *(s16x8*)(cbh + (size_t)k * 64 + c0) = ph.v;
    }
}

// Fused pre_vq + VQ, register-resident z. 1024 blocks x 128 positions.
__global__ __launch_bounds__(256) void vqf_k(
    const bf16* __restrict__ A, const bf16* __restrict__ pvw,
    const float* __restrict__ pvb, const float* __restrict__ cbf,
    const bf16* __restrict__ cbh, const float* __restrict__ sc,
    bf16* __restrict__ q, float* __restrict__ counts,
    float* __restrict__ loss_sum)
{
    __shared__ bf16 sX[128 * 128];           // 32KB A tile
    __shared__ float sSC[512];
    __shared__ float sHist[512];
    __shared__ int   sBK[128];
    __shared__ float sWS[4];
    const int tid = threadIdx.x;
    sSC[tid] = sc[tid]; sSC[tid + 256] = sc[tid + 256];
    sHist[tid] = 0.f;   sHist[tid + 256] = 0.f;

    const int n0 = blockIdx.x * 128;
    for (int i = tid; i < 128 * 16; i += 256) {
        int t = i >> 4, c0 = (i & 15) * 8;
        s16x8 v = *(const s16x8*)(A + (size_t)(n0 + t) * 128 + c0);
        int byte = ((t * 128 + c0) << 1) ^ ((t & 7) << 4);
        *(s16x8*)((char*)sX + byte) = v;
    }
    __syncthreads();

    const int lane = tid & 63, wid = tid >> 6;
    const int lr = lane & 15, kg = lane >> 4;
    const int pw0 = wid * 32;                // wave's position base in tile
    const f32x4 zf4 = {0.f, 0.f, 0.f, 0.f};

    // ---- pre_vq GEMM: zacc[cf][lf] -> ch=cf*16+kg*4+j, pos=pw0+lf*16+lr ----
    f32x4 zacc[4][2];
#pragma unroll
    for (int cf = 0; cf < 4; ++cf)
#pragma unroll
        for (int lf = 0; lf < 2; ++lf) zacc[cf][lf] = zf4;
#pragma unroll
    for (int ks = 0; ks < 4; ++ks) {
        s16x8 af[4];
#pragma unroll
        for (int cf = 0; cf < 4; ++cf)
            af[cf] = *(const s16x8*)(pvw + (size_t)(cf * 16 + lr) * 128 + ks * 32 + kg * 8);
        s16x8 bfr[2];
#pragma unroll
        for (int lf = 0; lf < 2; ++lf) {
            int t = pw0 + lf * 16 + lr;
            int byte = ((t * 128 + ks * 32 + kg * 8) << 1) ^ ((t & 7) << 4);
            bfr[lf] = *(const s16x8*)((const char*)sX + byte);
        }
#pragma unroll
        for (int cf = 0; cf < 4; ++cf)
#pragma unroll
            for (int lf = 0; lf < 2; ++lf)
                zacc[cf][lf] = MFMA16(af[cf], bfr[lf], zacc[cf][lf]);
    }
    // bias
#pragma unroll
    for (int cf = 0; cf < 4; ++cf) {
        float4 bv = *(const float4*)(pvb + cf * 16 + kg * 4);
#pragma unroll
        for (int lf = 0; lf < 2; ++lf) {
            zacc[cf][lf][0] += bv.x; zacc[cf][lf][1] += bv.y;
            zacc[cf][lf][2] += bv.z; zacc[cf][lf][3] += bv.w;
        }
    }

    // ---- build B-fragments via cross-lane shuffles (hi/lo split) ----
    // frag elem i of (lf,ks): ch = ks*32+kg*8+i, lives at lane (lr, (2kg+(i>=4))&3),
    // reg zacc[2ks+(kg>>1)][lf][i&3].
    const int srcA = lr + (((2 * kg) & 3) << 4);
    const int srcB = lr + (((2 * kg + 1) & 3) << 4);
    const bool hiCf = (kg >> 1) != 0;
    s16x8 bh[2][2], bl[2][2];
#pragma unroll
    for (int lf = 0; lf < 2; ++lf)
#pragma unroll
        for (int ks = 0; ks < 2; ++ks) {
            union { unsigned short u[8]; s16x8 s; } ph, pl;
#pragma unroll
            for (int i = 0; i < 4; ++i) {
                float a0 = __shfl(zacc[2 * ks][lf][i], srcA, 64);
                float a1 = __shfl(zacc[2 * ks + 1][lf][i], srcA, 64);
                float va = hiCf ? a1 : a0;
                float b0 = __shfl(zacc[2 * ks][lf][i], srcB, 64);
                float b1 = __shfl(zacc[2 * ks + 1][lf][i], srcB, 64);
                float vb = hiCf ? b1 : b0;
                unsigned short h = bfbits(va);
                ph.u[i] = h; pl.u[i] = bfbits(va - bf2f(h));
                h = bfbits(vb);
                ph.u[4 + i] = h; pl.u[4 + i] = bfbits(vb - bf2f(h));
            }
            bh[lf][ks] = ph.s; bl[lf][ks] = pl.s;
        }

    // ---- distance GEMM + register argmin (c_lo dropped: err ~2e-8) ----
    float bestd[2] = {3.4e38f, 3.4e38f};
    int   bestk[2] = {0, 0};
#pragma unroll 4
    for (int cf = 0; cf < 32; ++cf) {
        int code = cf * 16 + lr;
        const bf16* ph = cbh + code * 64 + kg * 8;
        s16x8 ah0 = *(const s16x8*)ph;
        s16x8 ah1 = *(const s16x8*)(ph + 32);
        float s0 = sSC[cf * 16 + kg * 4 + 0];
        float s1 = sSC[cf * 16 + kg * 4 + 1];
        float s2 = sSC[cf * 16 + kg * 4 + 2];
        float s3 = sSC[cf * 16 + kg * 4 + 3];
        int kb = cf * 16 + kg * 4;
#pragma unroll
        for (int lf = 0; lf < 2; ++lf) {
            f32x4 acc = MFMA16(ah0, bh[lf][0], zf4);
            acc = MFMA16(ah1, bh[lf][1], acc);
            acc = MFMA16(ah0, bl[lf][0], acc);   // c_hi . z_lo
            acc = MFMA16(ah1, bl[lf][1], acc);
            float d0 = fmaf(acc[0], -2.f, s0);
            float d1 = fmaf(acc[1], -2.f, s1);
            float d2 = fmaf(acc[2], -2.f, s2);
            float d3 = fmaf(acc[3], -2.f, s3);
            if (d0 < bestd[lf]) { bestd[lf] = d0; bestk[lf] = kb; }
            if (d1 < bestd[lf]) { bestd[lf] = d1; bestk[lf] = kb + 1; }
            if (d2 < bestd[lf]) { bestd[lf] = d2; bestk[lf] = kb + 2; }
            if (d3 < bestd[lf]) { bestd[lf] = d3; bestk[lf] = kb + 3; }
        }
    }
#pragma unroll
    for (int lf = 0; lf < 2; ++lf) {
#pragma unroll
        for (int off = 16; off <= 32; off <<= 1) {
            float od = __shfl_xor(bestd[lf], off, 64);
            int   ok = __shfl_xor(bestk[lf], off, 64);
            if (od < bestd[lf] || (od == bestd[lf] && ok < bestk[lf])) {
                bestd[lf] = od; bestk[lf] = ok;
            }
        }
        if (kg == 0) sBK[pw0 + lf * 16 + lr] = bestk[lf];
    }
    __syncthreads();

    // ---- loss + hist + q-write in fragment layout ----
    float lsum = 0.f;
#pragma unroll
    for (int lf = 0; lf < 2; ++lf) {
        int posl = pw0 + lf * 16 + lr;
        int k = sBK[posl];
        if (kg == 0) atomicAdd(&sHist[k], 1.f);
        const float* qp = cbf + (size_t)k * 64 + kg * 4;
        bf16* qo = q + (size_t)(n0 + posl) * 64 + kg * 4;
#pragma unroll
        for (int cf = 0; cf < 4; ++cf) {
            float4 qv = *(const float4*)(qp + cf * 16);
            float d0 = qv.x - zacc[cf][lf][0];
            float d1 = qv.y - zacc[cf][lf][1];
            float d2 = qv.z - zacc[cf][lf][2];
            float d3 = qv.w - zacc[cf][lf][3];
            lsum = fmaf(d0, d0, fmaf(d1, d1, fmaf(d2, d2, fmaf(d3, d3, lsum))));
            uint2 pk;
            pk.x = (unsigned)bfbits(qv.x) | ((unsigned)bfbits(qv.y) << 16);
            pk.y = (unsigned)bfbits(qv.z) | ((unsigned)bfbits(qv.w) << 16);
            *(uint2*)(qo + cf * 16) = pk;
        }
    }
#pragma unroll
    for (int off = 32; off > 0; off >>= 1) lsum += __shfl_down(lsum, off, 64);
    if (lane == 0) sWS[wid] = lsum;
    __syncthreads();
    if (tid == 0) atomicAdd(loss_sum, sWS[0] + sWS[1] + sWS[2] + sWS[3]);
    float c0v = sHist[tid];       if (c0v != 0.f) atomicAdd(&counts[tid], c0v);
    float c1v = sHist[tid + 256]; if (c1v != 0.f) atomicAdd(&counts[tid + 256], c1v);
}

__global__ __launch_bounds__(512) void finalize_k(
    const float* __restrict__ counts, const float* __restrict__ loss_sum,
    float* __restrict__ d_out, int out_size)
{
    __shared__ float ws2[8];
    const int tid = threadIdx.x;
    float p = counts[tid] * (1.f / 131072.f);
    float e = p * logf(p + 1e-10f);
#pragma unroll
    for (int off = 32; off > 0; off >>= 1) e += __shfl_down(e, off, 64);
    const int lane = tid & 63, wid = tid >> 6;
    if (lane == 0) ws2[wid] = e;
    __syncthreads();
    if (tid == 0) {
        float s = 0.f;
        for (int i = 0; i < 8; ++i) s += ws2[i];
        d_out[0] = 1.25f * loss_sum[0] * (1.f / 8388608.f);  // (1+BETA)*mean
        d_out[out_size - 1] = expf(-s);
    }
}

extern "C" void kernel_launch(void* const* d_in, const int* in_sizes, int n_in,
                              void* d_out, int out_size, void* d_ws, size_t ws_size,
                              hipStream_t stream)
{
    const float* x        = (const float*)d_in[0];
    const float* enc_w1   = (const float*)d_in[1];
    const float* enc_b1   = (const float*)d_in[2];
    const float* enc_b2   = (const float*)d_in[4];
    const float* enc_b3   = (const float*)d_in[6];
    const float* pre_vq_b = (const float*)d_in[12];
    const float* cb       = (const float*)d_in[13];
    const float* dec_b1   = (const float*)d_in[15];
    const float* ct1_b    = (const float*)d_in[21];
    const float* ct2_w    = (const float*)d_in[22];
    const float* ct2_b    = (const float*)d_in[23];
    float* out = (float*)d_out;

    char* base = (char*)d_ws;
    bf16*  wb   = (bf16*)base;                            // 13 x 64K bf16 = 1.7MB
    bf16*  Abf  = (bf16*)(base + ((size_t)2   << 20));    // 33.5MB
    bf16*  Bbf  = (bf16*)(base + ((size_t)40  << 20));    // 33.5MB
    bf16*  Qbf  = (bf16*)(base + ((size_t)78  << 20));    // 16.7MB
    bf16*  cbh  = (bf16*)(base + ((size_t)96  << 20));    // 64KB
    float* sc   = (float*)(base + ((size_t)96  << 20) + 131072);
    float* cnt  = sc + 512;
    float* lsum = cnt + 512;

    hipMemsetAsync(cnt, 0, 513 * sizeof(float), stream);

    dim3 blk(256);
    dim3 g16(16, 128);

    wx_k<<<dim3(13, 8), blk, 0, stream>>>(
        (const float*)d_in[3], (const float*)d_in[5], (const float*)d_in[7],
        (const float*)d_in[8], (const float*)d_in[9], (const float*)d_in[10],
        (const float*)d_in[11], (const float*)d_in[14], (const float*)d_in[16],
        (const float*)d_in[17], (const float*)d_in[18], (const float*)d_in[19],
        (const float*)d_in[20], wb);
    cbprep_k<<<2, blk, 0, stream>>>(cb, cbh, sc);

    enc12_k<<<g16, blk, 0, stream>>>(x, enc_w1, enc_b1, wb + 0 * 65536, enc_b2, Bbf);
    gconv_k<128,128,3,M_S1,false,false,true ><<<g16, blk, 0, stream>>>(
        Bbf, wb + 1 * 65536, enc_b3, Abf, 1024, 1024);
    fres_k<false><<<g16, blk, 0, stream>>>(Abf, wb + 2 * 65536, wb + 3 * 65536, Bbf);
    fres_k<true ><<<g16, blk, 0, stream>>>(Bbf, wb + 4 * 65536, wb + 5 * 65536, Abf);

    vqf_k<<<1024, blk, 0, stream>>>(Abf, wb + 6 * 65536, pre_vq_b, cb,
                                    cbh, sc, Qbf, cnt, lsum);

    gconv_k<64,128,3,M_S1,false,false,true ><<<g16, blk, 0, stream>>>(
        Qbf, wb + 7 * 65536, dec_b1, Abf, 1024, 1024);
    fres_k<false><<<g16, blk, 0, stream>>>(Abf, wb + 8 * 65536, wb + 9 * 65536, Bbf);
    fres_k<true ><<<g16, blk, 0, stream>>>(Bbf, wb + 10 * 65536, wb + 11 * 65536, Abf);
    gconv_k<128,64,2,M_CT,false,true ,true ><<<g16, blk, 0, stream>>>(
        Abf, wb + 12 * 65536, ct1_b, Bbf, 1024, 2048);

    ct2_k<<<dim3(8, 128), blk, 0, stream>>>(Bbf, ct2_w, ct2_b, out + 1);
    finalize_k<<<1, 512, 0, stream>>>(cnt, lsum, out, out_size);
}

// Round 8
// 358.557 us; speedup vs baseline: 1.1678x; 1.1678x over previous
//
#include <hip/hip_runtime.h>
#include <hip/hip_bf16.h>
#include <math.h>

using bf16 = __hip_bfloat16;
typedef __attribute__((ext_vector_type(4))) float f32x4;
typedef __attribute__((ext_vector_type(8))) short s16x8;

#define MFMA16(a,b,c) __builtin_amdgcn_mfma_f32_16x16x32_bf16((a),(b),(c),0,0,0)

// ---------------------------------------------------------------------------
// VQ-VAE forward. B=128, L=4096, H=128, RH=64, D=64, K=512.
// Channel-last bf16. Two fused chain kernels (encmid / decmid) + fused
// enc1+enc2 + fused pre_vq+VQ (round-6 proven version) + ct2.
// ---------------------------------------------------------------------------

__device__ inline float bf2f(unsigned short u) {
    union { float f; unsigned v; } c; c.v = ((unsigned)u) << 16; return c.f;
}
__device__ inline unsigned short bfbits(float f) {
    union { bf16 h; unsigned short u; } c; c.h = __float2bfloat16(f); return c.u;
}
__device__ inline s16x8 relu8(s16x8 v) {
#pragma unroll
    for (int j = 0; j < 8; ++j)
        v[j] = (short)(((unsigned short)v[j] & 0x8000u) ? 0 : (unsigned short)v[j]);
    return v;
}

// ===========================================================================
// encmid: enc3 (128->128 K3) + res1 + res2 + final relu.  Bbf -> Abf.
// Window: 80 rows = global [l0-8, l0+71]; X staged on [l0-16, l0+79].
// ===========================================================================
__global__ __launch_bounds__(256) void encmid_k(
    const bf16* __restrict__ in, const bf16* __restrict__ w3t,
    const float* __restrict__ b3, const bf16* __restrict__ r1w1,
    const bf16* __restrict__ r1w2, const bf16* __restrict__ r2w1,
    const bf16* __restrict__ r2w2, bf16* __restrict__ out)
{
    __shared__ bf16 sX[96 * 128];
    __shared__ bf16 sY[80 * 128];
    __shared__ bf16 sH[80 * 64];
    const int tid = threadIdx.x;
    const int b   = blockIdx.y;
    const int l0  = blockIdx.x * 64;
    const bf16* inb = in + (size_t)b * 1024 * 128;

    for (int i = tid; i < 96 * 16; i += 256) {
        int t = i >> 4, c0 = (i & 15) * 8;
        int g = l0 - 16 + t;
        s16x8 v = {};
        if (g >= 0 && g < 1024) v = *(const s16x8*)(inb + (size_t)g * 128 + c0);
        int byte = ((t * 128 + c0) << 1) ^ ((t & 7) << 4);
        *(s16x8*)((char*)sX + byte) = v;
    }
    __syncthreads();

    const int lane = tid & 63;
    const int wid  = __builtin_amdgcn_readfirstlane(tid >> 6);
    const int lr   = lane & 15;
    const int kg   = lane >> 4;
    const f32x4 zf4 = {0.f, 0.f, 0.f, 0.f};

    // ---- phase 1: enc3 -> sY (80 rows x 128 co), bias, OOR-zero ----
    {
        const int co0 = wid * 32;
        f32x4 acc[2][5];
#pragma unroll
        for (int cf = 0; cf < 2; ++cf)
#pragma unroll
            for (int lf = 0; lf < 5; ++lf) acc[cf][lf] = zf4;
#pragma unroll
        for (int k = 0; k < 3; ++k) {
            const bf16* Ab = w3t + (size_t)k * 128 * 128;
#pragma unroll
            for (int ks = 0; ks < 4; ++ks) {
                s16x8 af[2];
#pragma unroll
                for (int cf = 0; cf < 2; ++cf)
                    af[cf] = *(const s16x8*)(Ab + (co0 + cf * 16 + lr) * 128 + ks * 32 + kg * 8);
                s16x8 bfr[5];
#pragma unroll
                for (int lf = 0; lf < 5; ++lf) {
                    int tx = lf * 16 + lr + 7 + k;
                    int byte = ((tx * 128 + ks * 32 + kg * 8) << 1) ^ ((tx & 7) << 4);
                    bfr[lf] = *(const s16x8*)((const char*)sX + byte);
                }
#pragma unroll
                for (int cf = 0; cf < 2; ++cf)
#pragma unroll
                    for (int lf = 0; lf < 5; ++lf)
                        acc[cf][lf] = MFMA16(af[cf], bfr[lf], acc[cf][lf]);
            }
        }
#pragma unroll
        for (int cf = 0; cf < 2; ++cf)
#pragma unroll
            for (int lf = 0; lf < 5; ++lf) {
                int row = lf * 16 + lr;
                int p   = l0 - 8 + row;
                int cb0 = co0 + cf * 16 + kg * 4;
                bool ok = (p >= 0 && p < 1024);
                float r[4];
#pragma unroll
                for (int j = 0; j < 4; ++j)
                    r[j] = ok ? (acc[cf][lf][j] + b3[cb0 + j]) : 0.f;
                uint2 pk;
                pk.x = (unsigned)bfbits(r[0]) | ((unsigned)bfbits(r[1]) << 16);
                pk.y = (unsigned)bfbits(r[2]) | ((unsigned)bfbits(r[3]) << 16);
                int byte = ((row * 128 + cb0) << 1) ^ ((row & 7) << 4);
                *(uint2*)((char*)sY + byte) = pk;
            }
    }
    __syncthreads();

    // ---- phases 2..5: two res blocks ----
#pragma unroll 1
    for (int blk = 0; blk < 2; ++blk) {
        const bf16* w1 = blk ? r2w1 : r1w1;
        // H = relu(conv3tap(relu(Y)))
        {
            const int co0 = wid * 16;
            f32x4 acc[5];
#pragma unroll
            for (int lf = 0; lf < 5; ++lf) acc[lf] = zf4;
#pragma unroll
            for (int k = 0; k < 3; ++k) {
                const bf16* Ab = w1 + (size_t)k * 64 * 128;
#pragma unroll
                for (int ks = 0; ks < 4; ++ks) {
                    s16x8 a = *(const s16x8*)(Ab + (co0 + lr) * 128 + ks * 32 + kg * 8);
                    s16x8 bfr[5];
#pragma unroll
                    for (int lf = 0; lf < 5; ++lf) {
                        int ry = lf * 16 + lr + k - 1;
                        ry = (ry < 0) ? 0 : (ry > 79 ? 79 : ry);
                        int byte = ((ry * 128 + ks * 32 + kg * 8) << 1) ^ ((ry & 7) << 4);
                        bfr[lf] = relu8(*(const s16x8*)((const char*)sY + byte));
                    }
#pragma unroll
                    for (int lf = 0; lf < 5; ++lf)
                        acc[lf] = MFMA16(a, bfr[lf], acc[lf]);
                }
            }
#pragma unroll
            for (int lf = 0; lf < 5; ++lf) {
                int row = lf * 16 + lr;
                int ch0 = co0 + kg * 4;
                uint2 pk;
                pk.x = (unsigned)bfbits(fmaxf(acc[lf][0], 0.f)) |
                       ((unsigned)bfbits(fmaxf(acc[lf][1], 0.f)) << 16);
                pk.y = (unsigned)bfbits(fmaxf(acc[lf][2], 0.f)) |
                       ((unsigned)bfbits(fmaxf(acc[lf][3], 0.f)) << 16);
                int byte = ((row * 64 + ch0) << 1) ^ ((row & 7) << 4);
                *(uint2*)((char*)sH + byte) = pk;
            }
        }
        __syncthreads();

        if (blk == 0) {
            // Y += r1w2 * H (in place, OOR-zero)
            const int co0 = wid * 32;
            f32x4 acc[2][5];
#pragma unroll
            for (int cf = 0; cf < 2; ++cf)
#pragma unroll
                for (int lf = 0; lf < 5; ++lf) acc[cf][lf] = zf4;
#pragma unroll
            for (int ks = 0; ks < 2; ++ks) {
                s16x8 af[2];
#pragma unroll
                for (int cf = 0; cf < 2; ++cf)
                    af[cf] = *(const s16x8*)(r1w2 + (size_t)(co0 + cf * 16 + lr) * 64 + ks * 32 + kg * 8);
                s16x8 bfr[5];
#pragma unroll
                for (int lf = 0; lf < 5; ++lf) {
                    int row = lf * 16 + lr;
                    int byte = ((row * 64 + ks * 32 + kg * 8) << 1) ^ ((row & 7) << 4);
                    bfr[lf] = *(const s16x8*)((const char*)sH + byte);
                }
#pragma unroll
                for (int cf = 0; cf < 2; ++cf)
#pragma unroll
                    for (int lf = 0; lf < 5; ++lf)
                        acc[cf][lf] = MFMA16(af[cf], bfr[lf], acc[cf][lf]);
            }
#pragma unroll
            for (int cf = 0; cf < 2; ++cf)
#pragma unroll
                for (int lf = 0; lf < 5; ++lf) {
                    int row = lf * 16 + lr;
                    int p   = l0 - 8 + row;
                    int cb0 = co0 + cf * 16 + kg * 4;
                    int byte = ((row * 128 + cb0) << 1) ^ ((row & 7) << 4);
                    uint2 old = *(const uint2*)((const char*)sY + byte);
                    bool ok = (p >= 0 && p < 1024);
                    float r[4];
                    r[0] = acc[cf][lf][0] + bf2f((unsigned short)(old.x & 0xffff));
                    r[1] = acc[cf][lf][1] + bf2f((unsigned short)(old.x >> 16));
                    r[2] = acc[cf][lf][2] + bf2f((unsigned short)(old.y & 0xffff));
                    r[3] = acc[cf][lf][3] + bf2f((unsigned short)(old.y >> 16));
                    uint2 pk;
                    pk.x = ok ? ((unsigned)bfbits(r[0]) | ((unsigned)bfbits(r[1]) << 16)) : 0u;
                    pk.y = ok ? ((unsigned)bfbits(r[2]) | ((unsigned)bfbits(r[3]) << 16)) : 0u;
                    *(uint2*)((char*)sY + byte) = pk;
                }
            __syncthreads();
        } else {
            // final: out = relu(Y + r2w2 * H) on rows 8..71 -> global
            const int co0 = wid * 32;
            f32x4 acc[2][4];
#pragma unroll
            for (int cf = 0; cf < 2; ++cf)
#pragma unroll
                for (int lf = 0; lf < 4; ++lf) acc[cf][lf] = zf4;
#pragma unroll
            for (int ks = 0; ks < 2; ++ks) {
                s16x8 af[2];
#pragma unroll
                for (int cf = 0; cf < 2; ++cf)
                    af[cf] = *(const s16x8*)(r2w2 + (size_t)(co0 + cf * 16 + lr) * 64 + ks * 32 + kg * 8);
                s16x8 bfr[4];
#pragma unroll
                for (int lf = 0; lf < 4; ++lf) {
                    int row = 8 + lf * 16 + lr;
                    int byte = ((row * 64 + ks * 32 + kg * 8) << 1) ^ ((row & 7) << 4);
                    bfr[lf] = *(const s16x8*)((const char*)sH + byte);
                }
#pragma unroll
                for (int cf = 0; cf < 2; ++cf)
#pragma unroll
                    for (int lf = 0; lf < 4; ++lf)
                        acc[cf][lf] = MFMA16(af[cf], bfr[lf], acc[cf][lf]);
            }
#pragma unroll
            for (int cf = 0; cf < 2; ++cf)
#pragma unroll
                for (int lf = 0; lf < 4; ++lf) {
                    int row = 8 + lf * 16 + lr;
                    int cb0 = co0 + cf * 16 + kg * 4;
                    int byte = ((row * 128 + cb0) << 1) ^ ((row & 7) << 4);
                    uint2 old = *(const uint2*)((const char*)sY + byte);
                    float r[4];
                    r[0] = fmaxf(acc[cf][lf][0] + bf2f((unsigned short)(old.x & 0xffff)), 0.f);
                    r[1] = fmaxf(acc[cf][lf][1] + bf2f((unsigned short)(old.x >> 16)), 0.f);
                    r[2] = fmaxf(acc[cf][lf][2] + bf2f((unsigned short)(old.y & 0xffff)), 0.f);
                    r[3] = fmaxf(acc[cf][lf][3] + bf2f((unsigned short)(old.y >> 16)), 0.f);
                    uint2 pk;
                    pk.x = (unsigned)bfbits(r[0]) | ((unsigned)bfbits(r[1]) << 16);
                    pk.y = (unsigned)bfbits(r[2]) | ((unsigned)bfbits(r[3]) << 16);
                    *(uint2*)(out + ((size_t)b * 1024 + l0 + lf * 16 + lr) * 128 + cb0) = pk;
                }
        }
    }
}

// ===========================================================================
// decmid: dec1 (64->128 K3 bias) + res1 + res2(+relu) + ct1 (convT 128->64,
// x2 upsample, bias+relu).  Qbf -> (b,2048,64) bf16.
// ===========================================================================
__global__ __launch_bounds__(256) void decmid_k(
    const bf16* __restrict__ qin, const bf16* __restrict__ dw1,
    const float* __restrict__ db1, const bf16* __restrict__ r1w1,
    const bf16* __restrict__ r1w2, const bf16* __restrict__ r2w1,
    const bf16* __restrict__ r2w2, const bf16* __restrict__ ct1w,
    const float* __restrict__ ct1b, bf16* __restrict__ out)
{
    __shared__ bf16 sQ[96 * 64];
    __shared__ bf16 sY[80 * 128];
    __shared__ bf16 sH[80 * 64];
    const int tid = threadIdx.x;
    const int b   = blockIdx.y;
    const int l0  = blockIdx.x * 64;
    const bf16* inb = qin + (size_t)b * 1024 * 64;

    for (int i = tid; i < 96 * 8; i += 256) {
        int t = i >> 3, c0 = (i & 7) * 8;
        int g = l0 - 16 + t;
        s16x8 v = {};
        if (g >= 0 && g < 1024) v = *(const s16x8*)(inb + (size_t)g * 64 + c0);
        int byte = ((t * 64 + c0) << 1) ^ ((t & 7) << 4);
        *(s16x8*)((char*)sQ + byte) = v;
    }
    __syncthreads();

    const int lane = tid & 63;
    const int wid  = __builtin_amdgcn_readfirstlane(tid >> 6);
    const int lr   = lane & 15;
    const int kg   = lane >> 4;
    const f32x4 zf4 = {0.f, 0.f, 0.f, 0.f};

    // ---- phase 1: dec1 -> sY, bias, OOR-zero ----
    {
        const int co0 = wid * 32;
        f32x4 acc[2][5];
#pragma unroll
        for (int cf = 0; cf < 2; ++cf)
#pragma unroll
            for (int lf = 0; lf < 5; ++lf) acc[cf][lf] = zf4;
#pragma unroll
        for (int k = 0; k < 3; ++k) {
            const bf16* Ab = dw1 + (size_t)k * 128 * 64;
#pragma unroll
            for (int ks = 0; ks < 2; ++ks) {
                s16x8 af[2];
#pragma unroll
                for (int cf = 0; cf < 2; ++cf)
                    af[cf] = *(const s16x8*)(Ab + (co0 + cf * 16 + lr) * 64 + ks * 32 + kg * 8);
                s16x8 bfr[5];
#pragma unroll
                for (int lf = 0; lf < 5; ++lf) {
                    int tx = lf * 16 + lr + 7 + k;
                    int byte = ((tx * 64 + ks * 32 + kg * 8) << 1) ^ ((tx & 7) << 4);
                    bfr[lf] = *(const s16x8*)((const char*)sQ + byte);
                }
#pragma unroll
                for (int cf = 0; cf < 2; ++cf)
#pragma unroll
                    for (int lf = 0; lf < 5; ++lf)
                        acc[cf][lf] = MFMA16(af[cf], bfr[lf], acc[cf][lf]);
            }
        }
#pragma unroll
        for (int cf = 0; cf < 2; ++cf)
#pragma unroll
            for (int lf = 0; lf < 5; ++lf) {
                int row = lf * 16 + lr;
                int p   = l0 - 8 + row;
                int cb0 = co0 + cf * 16 + kg * 4;
                bool ok = (p >= 0 && p < 1024);
                float r[4];
#pragma unroll
                for (int j = 0; j < 4; ++j)
                    r[j] = ok ? (acc[cf][lf][j] + db1[cb0 + j]) : 0.f;
                uint2 pk;
                pk.x = (unsigned)bfbits(r[0]) | ((unsigned)bfbits(r[1]) << 16);
                pk.y = (unsigned)bfbits(r[2]) | ((unsigned)bfbits(r[3]) << 16);
                int byte = ((row * 128 + cb0) << 1) ^ ((row & 7) << 4);
                *(uint2*)((char*)sY + byte) = pk;
            }
    }
    __syncthreads();

    // ---- res blocks ----
#pragma unroll 1
    for (int blk = 0; blk < 2; ++blk) {
        const bf16* w1 = blk ? r2w1 : r1w1;
        const bf16* w2 = blk ? r2w2 : r1w2;
        {
            const int co0 = wid * 16;
            f32x4 acc[5];
#pragma unroll
            for (int lf = 0; lf < 5; ++lf) acc[lf] = zf4;
#pragma unroll
            for (int k = 0; k < 3; ++k) {
                const bf16* Ab = w1 + (size_t)k * 64 * 128;
#pragma unroll
                for (int ks = 0; ks < 4; ++ks) {
                    s16x8 a = *(const s16x8*)(Ab + (co0 + lr) * 128 + ks * 32 + kg * 8);
                    s16x8 bfr[5];
#pragma unroll
                    for (int lf = 0; lf < 5; ++lf) {
                        int ry = lf * 16 + lr + k - 1;
                        ry = (ry < 0) ? 0 : (ry > 79 ? 79 : ry);
                        int byte = ((ry * 128 + ks * 32 + kg * 8) << 1) ^ ((ry & 7) << 4);
                        bfr[lf] = relu8(*(const s16x8*)((const char*)sY + byte));
                    }
#pragma unroll
                    for (int lf = 0; lf < 5; ++lf)
                        acc[lf] = MFMA16(a, bfr[lf], acc[lf]);
                }
            }
#pragma unroll
            for (int lf = 0; lf < 5; ++lf) {
                int row = lf * 16 + lr;
                int ch0 = co0 + kg * 4;
                uint2 pk;
                pk.x = (unsigned)bfbits(fmaxf(acc[lf][0], 0.f)) |
                       ((unsigned)bfbits(fmaxf(acc[lf][1], 0.f)) << 16);
                pk.y = (unsigned)bfbits(fmaxf(acc[lf][2], 0.f)) |
                       ((unsigned)bfbits(fmaxf(acc[lf][3], 0.f)) << 16);
                int byte = ((row * 64 + ch0) << 1) ^ ((row & 7) << 4);
                *(uint2*)((char*)sH + byte) = pk;
            }
        }
        __syncthreads();
        {
            // Y = [relu](Y + w2*H), OOR-zero; relu only on blk==1 (stack end)
            const int co0 = wid * 32;
            f32x4 acc[2][5];
#pragma unroll
            for (int cf = 0; cf < 2; ++cf)
#pragma unroll
                for (int lf = 0; lf < 5; ++lf) acc[cf][lf] = zf4;
#pragma unroll
            for (int ks = 0; ks < 2; ++ks) {
                s16x8 af[2];
#pragma unroll
                for (int cf = 0; cf < 2; ++cf)
                    af[cf] = *(const s16x8*)(w2 + (size_t)(co0 + cf * 16 + lr) * 64 + ks * 32 + kg * 8);
                s16x8 bfr[5];
#pragma unroll
                for (int lf = 0; lf < 5; ++lf) {
                    int row = lf * 16 + lr;
                    int byte = ((row * 64 + ks * 32 + kg * 8) << 1) ^ ((row & 7) << 4);
                    bfr[lf] = *(const s16x8*)((const char*)sH + byte);
                }
#pragma unroll
                for (int cf = 0; cf < 2; ++cf)
#pragma unroll
                    for (int lf = 0; lf < 5; ++lf)
                        acc[cf][lf] = MFMA16(af[cf], bfr[lf], acc[cf][lf]);
            }
#pragma unroll
            for (int cf = 0; cf < 2; ++cf)
#pragma unroll
                for (int lf = 0; lf < 5; ++lf) {
                    int row = lf * 16 + lr;
                    int p   = l0 - 8 + row;
                    int cb0 = co0 + cf * 16 + kg * 4;
                    int byte = ((row * 128 + cb0) << 1) ^ ((row & 7) << 4);
                    uint2 old = *(const uint2*)((const char*)sY + byte);
                    bool ok = (p >= 0 && p < 1024);
                    float r[4];
                    r[0] = acc[cf][lf][0] + bf2f((unsigned short)(old.x & 0xffff));
                    r[1] = acc[cf][lf][1] + bf2f((unsigned short)(old.x >> 16));
                    r[2] = acc[cf][lf][2] + bf2f((unsigned short)(old.y & 0xffff));
                    r[3] = acc[cf][lf][3] + bf2f((unsigned short)(old.y >> 16));
                    if (blk == 1)
#pragma unroll
                        for (int j = 0; j < 4; ++j) r[j] = fmaxf(r[j], 0.f);
                    uint2 pk;
                    pk.x = ok ? ((unsigned)bfbits(r[0]) | ((unsigned)bfbits(r[1]) << 16)) : 0u;
                    pk.y = ok ? ((unsigned)bfbits(r[2]) | ((unsigned)bfbits(r[3]) << 16)) : 0u;
                    *(uint2*)((char*)sY + byte) = pk;
                }
        }
        __syncthreads();
    }

    // ---- phase 6: ct1 convT -> global (b,2048,64) ----
    {
        const int co0 = (wid & 1) * 32;
        const int mh  = wid >> 1;
        f32x4 acc[2][2][2];   // [g][cf][j]
#pragma unroll
        for (int g = 0; g < 2; ++g)
#pragma unroll
            for (int cf = 0; cf < 2; ++cf)
#pragma unroll
                for (int j = 0; j < 2; ++j) acc[g][cf][j] = zf4;
#pragma unroll
        for (int g = 0; g < 2; ++g)
#pragma unroll
            for (int k = 0; k < 2; ++k) {
                const bf16* Ab = ct1w + (size_t)(g * 2 + k) * 64 * 128;
                const int doff = (g == 0) ? (k - 1) : k;
#pragma unroll
                for (int ks = 0; ks < 4; ++ks) {
                    s16x8 af[2];
#pragma unroll
                    for (int cf = 0; cf < 2; ++cf)
                        af[cf] = *(const s16x8*)(Ab + (co0 + cf * 16 + lr) * 128 + ks * 32 + kg * 8);
                    s16x8 bfr[2];
#pragma unroll
                    for (int j = 0; j < 2; ++j) {
                        int ty = 8 + (mh * 2 + j) * 16 + lr + doff;
                        int byte = ((ty * 128 + ks * 32 + kg * 8) << 1) ^ ((ty & 7) << 4);
                        bfr[j] = *(const s16x8*)((const char*)sY + byte);
                    }
#pragma unroll
                    for (int cf = 0; cf < 2; ++cf)
#pragma unroll
                        for (int j = 0; j < 2; ++j)
                            acc[g][cf][j] = MFMA16(af[cf], bfr[j], acc[g][cf][j]);
                }
            }
#pragma unroll
        for (int g = 0; g < 2; ++g)
#pragma unroll
            for (int cf = 0; cf < 2; ++cf)
#pragma unroll
                for (int j = 0; j < 2; ++j) {
                    int m   = (mh * 2 + j) * 16 + lr;
                    int cb0 = co0 + cf * 16 + kg * 4;
                    float r[4];
#pragma unroll
                    for (int jj = 0; jj < 4; ++jj)
                        r[jj] = fmaxf(acc[g][cf][j][jj] + ct1b[cb0 + jj], 0.f);
                    uint2 pk;
                    pk.x = (unsigned)bfbits(r[0]) | ((unsigned)bfbits(r[1]) << 16);
                    pk.y = (unsigned)bfbits(r[2]) | ((unsigned)bfbits(r[3]) << 16);
                    *(uint2*)(out + ((size_t)b * 2048 + 2 * (l0 + m) + g) * 64 + cb0) = pk;
                }
    }
}

// Fused enc1+enc2: x fp32 -> h1 (LDS) -> enc2 GEMM -> (b,1024,128) bf16 relu.
__global__ __launch_bounds__(256) void enc12_k(
    const float* __restrict__ x, const float* __restrict__ w1,
    const float* __restrict__ b1, const bf16* __restrict__ w2t,
    const float* __restrict__ b2, bf16* __restrict__ out)
{
    __shared__ float sXf[268];
    __shared__ float sW1[256];
    __shared__ float sB1[64];
    __shared__ bf16 sX[132 * 64];
    const int tid = threadIdx.x;
    const int b   = blockIdx.y;
    const int l0  = blockIdx.x * 64;
    const float* xb = x + (size_t)b * 4096;

    for (int i = tid; i < 266; i += 256) {
        int g = 4 * l0 - 3 + i;
        sXf[i] = (g >= 0 && g < 4096) ? xb[g] : 0.f;
    }
    if (tid < 256) sW1[tid] = w1[tid];
    if (tid < 64)  sB1[tid] = b1[tid];
    __syncthreads();

    for (int i = tid; i < 132 * 64; i += 256) {
        int t = i >> 6, c = i & 63;
        int p = (t < 66) ? 2 * (l0 + t) : 2 * (l0 + t - 66) - 1;
        float v = 0.f;
        if (p >= 0 && p < 2048) {
            int xi = 2 * p - 4 * l0 + 2;
            float a = sB1[c];
#pragma unroll
            for (int k = 0; k < 4; ++k) a = fmaf(sXf[xi + k], sW1[c * 4 + k], a);
            v = fmaxf(a, 0.f);
        }
        int byte = ((t * 64 + c) << 1) ^ ((t & 7) << 4);
        *(bf16*)((char*)sX + byte) = __float2bfloat16(v);
    }
    __syncthreads();

    const int lane = tid & 63;
    const int wid  = __builtin_amdgcn_readfirstlane(tid >> 6);
    const int co0  = wid * 32;
    const int lr   = lane & 15;
    const int kg   = lane >> 4;

    f32x4 acc[2][4];
#pragma unroll
    for (int cf = 0; cf < 2; ++cf)
#pragma unroll
        for (int lf = 0; lf < 4; ++lf) acc[cf][lf] = (f32x4){0.f, 0.f, 0.f, 0.f};

#pragma unroll
    for (int k = 0; k < 4; ++k) {
        const int roff = (k == 0) ? 66 : (k == 1) ? 0 : (k == 2) ? 67 : 1;
        const bf16* Ab = w2t + (size_t)k * 128 * 64;
#pragma unroll
        for (int ks = 0; ks < 2; ++ks) {
            s16x8 af[2];
#pragma unroll
            for (int cf = 0; cf < 2; ++cf)
                af[cf] = *(const s16x8*)(Ab + (co0 + cf * 16 + lr) * 64 + ks * 32 + kg * 8);
            s16x8 bfr[4];
#pragma unroll
            for (int lf = 0; lf < 4; ++lf) {
                int t = roff + lf * 16 + lr;
                int byte = ((t * 64 + ks * 32 + kg * 8) << 1) ^ ((t & 7) << 4);
                bfr[lf] = *(const s16x8*)((const char*)sX + byte);
            }
#pragma unroll
            for (int cf = 0; cf < 2; ++cf)
#pragma unroll
                for (int lf = 0; lf < 4; ++lf)
                    acc[cf][lf] = MFMA16(af[cf], bfr[lf], acc[cf][lf]);
        }
    }

#pragma unroll
    for (int cf = 0; cf < 2; ++cf)
#pragma unroll
        for (int lf = 0; lf < 4; ++lf) {
            int cb0  = co0 + cf * 16 + kg * 4;
            int lcol = lf * 16 + lr;
            float r[4];
#pragma unroll
            for (int j = 0; j < 4; ++j)
                r[j] = fmaxf(acc[cf][lf][j] + b2[cb0 + j], 0.f);
            uint2 pk;
            pk.x = (unsigned)bfbits(r[0]) | ((unsigned)bfbits(r[1]) << 16);
            pk.y = (unsigned)bfbits(r[2]) | ((unsigned)bfbits(r[3]) << 16);
            *(uint2*)(out + ((size_t)b * 1024 + l0 + lcol) * 128 + cb0) = pk;
        }
}

// Final convT: 64->1 ch, x2 upsample; (b,l,c) bf16 in, fp32 out.
__global__ __launch_bounds__(256) void ct2_k(
    const bf16* __restrict__ in, const float* __restrict__ w,
    const float* __restrict__ bias, float* __restrict__ out)
{
    __shared__ bf16 sX[258 * 64];
    const int tid = threadIdx.x;
    const int b   = blockIdx.y;
    const int m0  = blockIdx.x * 256;
    const bf16* inb = in + (size_t)b * 2048 * 64;
    for (int i = tid; i < 258 * 8; i += 256) {
        int t = i >> 3, c0 = (i & 7) * 8;
        int g = m0 - 1 + t;
        s16x8 v = {};
        if (g >= 0 && g < 2048) v = *(const s16x8*)(inb + (size_t)g * 64 + c0);
        int byte = ((t * 64 + c0) << 1) ^ ((t & 7) << 4);
        *(s16x8*)((char*)sX + byte) = v;
    }
    __syncthreads();
    float e = bias[0], o = bias[0];
#pragma unroll
    for (int c0 = 0; c0 < 64; c0 += 8) {
        int t0 = tid, t1 = tid + 1, t2 = tid + 2;
        s16x8 vm1 = *(const s16x8*)((char*)sX + (((t0 * 64 + c0) << 1) ^ ((t0 & 7) << 4)));
        s16x8 v0  = *(const s16x8*)((char*)sX + (((t1 * 64 + c0) << 1) ^ ((t1 & 7) << 4)));
        s16x8 vp1 = *(const s16x8*)((char*)sX + (((t2 * 64 + c0) << 1) ^ ((t2 & 7) << 4)));
#pragma unroll
        for (int j = 0; j < 8; ++j) {
            int ci = c0 + j;
            float xm1 = bf2f((unsigned short)vm1[j]);
            float x0  = bf2f((unsigned short)v0[j]);
            float xp1 = bf2f((unsigned short)vp1[j]);
            e = fmaf(x0,  w[ci * 4 + 1], fmaf(xm1, w[ci * 4 + 3], e));
            o = fmaf(xp1, w[ci * 4 + 0], fmaf(x0,  w[ci * 4 + 2], o));
        }
    }
    int m = m0 + tid;
    out[(size_t)b * 4096 + 2 * m]     = e;
    out[(size_t)b * 4096 + 2 * m + 1] = o;
}

// Weight transform: fp32 conv weights -> bf16 [tap][co][ci] matrices.
__global__ __launch_bounds__(256) void wx_k(
    const float* ew2, const float* ew3, const float* er1a, const float* er1b,
    const float* er2a, const float* er2b, const float* pvw, const float* dw1,
    const float* dr1a, const float* dr1b, const float* dr2a, const float* dr2b,
    const float* ct1w, bf16* wb)
{
    const int job = blockIdx.x;
    bf16* dst = wb + (size_t)job * 65536;
    const float* src; int CO, CI, K;
    switch (job) {
        case 0:  src = ew2;  CO = 128; CI = 64;  K = 4; break;
        case 1:  src = ew3;  CO = 128; CI = 128; K = 3; break;
        case 2:  src = er1a; CO = 64;  CI = 128; K = 3; break;
        case 3:  src = er1b; CO = 128; CI = 64;  K = 1; break;
        case 4:  src = er2a; CO = 64;  CI = 128; K = 3; break;
        case 5:  src = er2b; CO = 128; CI = 64;  K = 1; break;
        case 6:  src = pvw;  CO = 64;  CI = 128; K = 1; break;
        case 7:  src = dw1;  CO = 128; CI = 64;  K = 3; break;
        case 8:  src = dr1a; CO = 64;  CI = 128; K = 3; break;
        case 9:  src = dr1b; CO = 128; CI = 64;  K = 1; break;
        case 10: src = dr2a; CO = 64;  CI = 128; K = 3; break;
        case 11: src = dr2b; CO = 128; CI = 64;  K = 1; break;
        default: src = ct1w; CO = 64;  CI = 128; K = 4; break;
    }
    const int tot = CO * CI * K;
    for (int i = blockIdx.y * 256 + threadIdx.x; i < tot; i += gridDim.y * 256) {
        if (job < 12) {
            int k = i / (CO * CI); int r = i - k * CO * CI;
            int co = r / CI; int ci = r - co * CI;
            dst[i] = __float2bfloat16(src[((size_t)co * CI + ci) * K + k]);
        } else {
            const int TAP[4] = {3, 1, 2, 0};   // [We0,We1,Wo0,Wo1]
            int g = i / (64 * 128); int r = i - g * 64 * 128;
            int co = r / 128; int ci = r - co * 128;
            dst[i] = __float2bfloat16(src[((size_t)ci * 64 + co) * 4 + TAP[g]]);
        }
    }
}

// codebook prep: fp32 norms + hi/lo bf16 split
__global__ __launch_bounds__(256) void cbprep_k(
    const float* __restrict__ cb, bf16* __restrict__ cbh, bf16* __restrict__ cbl,
    float* __restrict__ sc)
{
    int k = blockIdx.x * 256 + threadIdx.x;   // grid 2
    const float* c = cb + (size_t)k * 64;
    float s = 0.f;
#pragma unroll
    for (int d = 0; d < 64; ++d) s = fmaf(c[d], c[d], s);
    sc[k] = s;
#pragma unroll
    for (int c0 = 0; c0 < 64; c0 += 8) {
        union { unsigned short u[8]; s16x8 v; } ph, pl;
#pragma unroll
        for (int j = 0; j < 8; ++j) {
            float v = c[c0 + j];
            unsigned short h = bfbits(v);
            ph.u[j] = h;
            pl.u[j] = bfbits(v - bf2f(h));
        }
        *(s16x8*)(cbh + (size_t)k * 64 + c0) = ph.v;
        *(s16x8*)(cbl + (size_t)k * 64 + c0) = pl.v;
    }
}

// Fused pre_vq conv + VQ (round-6 proven version). A (b,1024,128) -> q bf16.
__global__ __launch_bounds__(256) void vqf_k(
    const bf16* __restrict__ A, const bf16* __restrict__ pvw,
    const float* __restrict__ pvb, const float* __restrict__ cbf,
    const bf16* __restrict__ cbh, const bf16* __restrict__ cbl,
    const float* __restrict__ sc, bf16* __restrict__ q,
    float* __restrict__ counts, float* __restrict__ loss_sum)
{
    __shared__ s16x8 sMemV[4096];            // 64KB: A tile, then z fp32 tile
    char* sMem = (char*)sMemV;
    __shared__ float sSC[512];
    __shared__ float sHist[512];
    __shared__ int   sBK[256];
    __shared__ float sWS[4];
    const int tid = threadIdx.x;
    sSC[tid] = sc[tid]; sSC[tid + 256] = sc[tid + 256];
    sHist[tid] = 0.f;   sHist[tid + 256] = 0.f;

    const int n0blk = blockIdx.x * 256;
    for (int i = tid; i < 256 * 16; i += 256) {
        int t = i >> 4, c0 = (i & 15) * 8;
        s16x8 v = *(const s16x8*)(A + (size_t)(n0blk + t) * 128 + c0);
        int byte = ((t * 128 + c0) << 1) ^ ((t & 7) << 4);
        *(s16x8*)(sMem + byte) = v;
    }
    __syncthreads();

    const int lane = tid & 63, wid = tid >> 6;
    const int lr = lane & 15, kg = lane >> 4;
    const int pw0 = wid * 64;
    const f32x4 zf4 = {0.f, 0.f, 0.f, 0.f};

    f32x4 zacc[4][4];
#pragma unroll
    for (int cf = 0; cf < 4; ++cf)
#pragma unroll
        for (int lf = 0; lf < 4; ++lf) zacc[cf][lf] = zf4;
#pragma unroll
    for (int ks = 0; ks < 4; ++ks) {
        s16x8 af[4];
#pragma unroll
        for (int cf = 0; cf < 4; ++cf)
            af[cf] = *(const s16x8*)(pvw + (size_t)(cf * 16 + lr) * 128 + ks * 32 + kg * 8);
        s16x8 bfr[4];
#pragma unroll
        for (int lf = 0; lf < 4; ++lf) {
            int t = pw0 + lf * 16 + lr;
            int byte = ((t * 128 + ks * 32 + kg * 8) << 1) ^ ((t & 7) << 4);
            bfr[lf] = *(const s16x8*)((const char*)sMem + byte);
        }
#pragma unroll
        for (int cf = 0; cf < 4; ++cf)
#pragma unroll
            for (int lf = 0; lf < 4; ++lf)
                zacc[cf][lf] = MFMA16(af[cf], bfr[lf], zacc[cf][lf]);
    }
    __syncthreads();

#pragma unroll
    for (int cf = 0; cf < 4; ++cf)
#pragma unroll
        for (int lf = 0; lf < 4; ++lf) {
            int pos = pw0 + lf * 16 + lr;
            int ch  = cf * 16 + kg * 4;
            float4 v = make_float4(zacc[cf][lf][0] + pvb[ch],
                                   zacc[cf][lf][1] + pvb[ch + 1],
                                   zacc[cf][lf][2] + pvb[ch + 2],
                                   zacc[cf][lf][3] + pvb[ch + 3]);
            int byte = ((pos * 64 + ch) << 2) ^ ((pos & 7) << 5);
            *(float4*)(sMem + byte) = v;
        }
    __syncthreads();

    s16x8 bh[4][2], bl[4][2];
#pragma unroll
    for (int lf = 0; lf < 4; ++lf)
#pragma unroll
        for (int ks = 0; ks < 2; ++ks) {
            int t = pw0 + lf * 16 + lr;
            int ch = ks * 32 + kg * 8;
            int byte = ((t * 64 + ch) << 2) ^ ((t & 7) << 5);
            float4 v0 = *(const float4*)(sMem + byte);
            float4 v1 = *(const float4*)(sMem + byte + 16);
            float v[8] = {v0.x, v0.y, v0.z, v0.w, v1.x, v1.y, v1.z, v1.w};
            union { unsigned short u[8]; s16x8 s; } ph, pl;
#pragma unroll
            for (int j = 0; j < 8; ++j) {
                unsigned short h = bfbits(v[j]);
                ph.u[j] = h;
                pl.u[j] = bfbits(v[j] - bf2f(h));
            }
            bh[lf][ks] = ph.s; bl[lf][ks] = pl.s;
        }

    float bestd[4] = {3.4e38f, 3.4e38f, 3.4e38f, 3.4e38f};
    int   bestk[4] = {0, 0, 0, 0};
#pragma unroll 2
    for (int cf = 0; cf < 32; ++cf) {
        int code = cf * 16 + lr;
        const bf16* ph = cbh + code * 64 + kg * 8;
        const bf16* pl = cbl + code * 64 + kg * 8;
        s16x8 ah0 = *(const s16x8*)ph;
        s16x8 ah1 = *(const s16x8*)(ph + 32);
        s16x8 al0 = *(const s16x8*)pl;
        s16x8 al1 = *(const s16x8*)(pl + 32);
        float s0 = sSC[cf * 16 + kg * 4 + 0];
        float s1 = sSC[cf * 16 + kg * 4 + 1];
        float s2 = sSC[cf * 16 + kg * 4 + 2];
        float s3 = sSC[cf * 16 + kg * 4 + 3];
        int kb = cf * 16 + kg * 4;
#pragma unroll
        for (int lf = 0; lf < 4; ++lf) {
            f32x4 acc = MFMA16(ah0, bh[lf][0], zf4);
            acc = MFMA16(ah1, bh[lf][1], acc);
            acc = MFMA16(al0, bh[lf][0], acc);
            acc = MFMA16(al1, bh[lf][1], acc);
            acc = MFMA16(ah0, bl[lf][0], acc);
            acc = MFMA16(ah1, bl[lf][1], acc);
            float d0 = fmaf(acc[0], -2.f, s0);
            float d1 = fmaf(acc[1], -2.f, s1);
            float d2 = fmaf(acc[2], -2.f, s2);
            float d3 = fmaf(acc[3], -2.f, s3);
            if (d0 < bestd[lf]) { bestd[lf] = d0; bestk[lf] = kb; }
            if (d1 < bestd[lf]) { bestd[lf] = d1; bestk[lf] = kb + 1; }
            if (d2 < bestd[lf]) { bestd[lf] = d2; bestk[lf] = kb + 2; }
            if (d3 < bestd[lf]) { bestd[lf] = d3; bestk[lf] = kb + 3; }
        }
    }
#pragma unroll
    for (int lf = 0; lf < 4; ++lf) {
#pragma unroll
        for (int off = 16; off <= 32; off <<= 1) {
            float od = __shfl_xor(bestd[lf], off, 64);
            int   ok = __shfl_xor(bestk[lf], off, 64);
            if (od < bestd[lf] || (od == bestd[lf] && ok < bestk[lf])) {
                bestd[lf] = od; bestk[lf] = ok;
            }
        }
        if (kg == 0) sBK[wid * 64 + lf * 16 + lr] = bestk[lf];
    }
    __syncthreads();

    const int n = n0blk + tid;
    const int k = sBK[tid];
    atomicAdd(&sHist[k], 1.f);
    float lsum = 0.f;
    const float* qp = cbf + (size_t)k * 64;
#pragma unroll
    for (int c0 = 0; c0 < 64; c0 += 8) {
        int byte = ((tid * 64 + c0) << 2) ^ ((tid & 7) << 5);
        float4 z0 = *(const float4*)(sMem + byte);
        float4 z1 = *(const float4*)(sMem + byte + 16);
        float4 q0 = *(const float4*)(qp + c0);
        float4 q1 = *(const float4*)(qp + c0 + 4);
        float qv[8] = {q0.x, q0.y, q0.z, q0.w, q1.x, q1.y, q1.z, q1.w};
        float zv[8] = {z0.x, z0.y, z0.z, z0.w, z1.x, z1.y, z1.z, z1.w};
        union { unsigned short u[8]; s16x8 v; } pk;
#pragma unroll
        for (int j = 0; j < 8; ++j) {
            float d = qv[j] - zv[j];
            lsum = fmaf(d, d, lsum);
            pk.u[j] = bfbits(qv[j]);
        }
        *(s16x8*)(q + (size_t)n * 64 + c0) = pk.v;
    }
#pragma unroll
    for (int off = 32; off > 0; off >>= 1) lsum += __shfl_down(lsum, off, 64);
    if ((tid & 63) == 0) sWS[tid >> 6] = lsum;
    __syncthreads();
    if (tid == 0) atomicAdd(loss_sum, sWS[0] + sWS[1] + sWS[2] + sWS[3]);
    float c0v = sHist[tid];       if (c0v != 0.f) atomicAdd(&counts[tid], c0v);
    float c1v = sHist[tid + 256]; if (c1v != 0.f) atomicAdd(&counts[tid + 256], c1v);
}

__global__ __launch_bounds__(512) void finalize_k(
    const float* __restrict__ counts, const float* __restrict__ loss_sum,
    float* __restrict__ d_out, int out_size)
{
    __shared__ float ws2[8];
    const int tid = threadIdx.x;
    float p = counts[tid] * (1.f / 131072.f);
    float e = p * logf(p + 1e-10f);
#pragma unroll
    for (int off = 32; off > 0; off >>= 1) e += __shfl_down(e, off, 64);
    const int lane = tid & 63, wid = tid >> 6;
    if (lane == 0) ws2[wid] = e;
    __syncthreads();
    if (tid == 0) {
        float s = 0.f;
        for (int i = 0; i < 8; ++i) s += ws2[i];
        d_out[0] = 1.25f * loss_sum[0] * (1.f / 8388608.f);  // (1+BETA)*mean
        d_out[out_size - 1] = expf(-s);
    }
}

extern "C" void kernel_launch(void* const* d_in, const int* in_sizes, int n_in,
                              void* d_out, int out_size, void* d_ws, size_t ws_size,
                              hipStream_t stream)
{
    const float* x        = (const float*)d_in[0];
    const float* enc_w1   = (const float*)d_in[1];
    const float* enc_b1   = (const float*)d_in[2];
    const float* enc_b2   = (const float*)d_in[4];
    const float* enc_b3   = (const float*)d_in[6];
    const float* pre_vq_b = (const float*)d_in[12];
    const float* cb       = (const float*)d_in[13];
    const float* dec_b1   = (const float*)d_in[15];
    const float* ct1_b    = (const float*)d_in[21];
    const float* ct2_w    = (const float*)d_in[22];
    const float* ct2_b    = (const float*)d_in[23];
    float* out = (float*)d_out;

    char* base = (char*)d_ws;
    bf16*  wb   = (bf16*)base;                            // 13 x 64K bf16
    bf16*  Abf  = (bf16*)(base + ((size_t)2   << 20));    // 33.5MB
    bf16*  Bbf  = (bf16*)(base + ((size_t)40  << 20));    // 33.5MB
    bf16*  Qbf  = (bf16*)(base + ((size_t)78  << 20));    // 16.7MB
    bf16*  cbh  = (bf16*)(base + ((size_t)96  << 20));    // 64KB
    bf16*  cbl  = (bf16*)(base + ((size_t)96  << 20) + 65536);
    float* sc   = (float*)(base + ((size_t)96  << 20) + 131072);
    float* cnt  = sc + 512;
    float* lsum = cnt + 512;

    hipMemsetAsync(cnt, 0, 513 * sizeof(float), stream);

    dim3 blk(256);
    dim3 g16(16, 128);

    wx_k<<<dim3(13, 8), blk, 0, stream>>>(
        (const float*)d_in[3], (const float*)d_in[5], (const float*)d_in[7],
        (const float*)d_in[8], (const float*)d_in[9], (const float*)d_in[10],
        (const float*)d_in[11], (const float*)d_in[14], (const float*)d_in[16],
        (const float*)d_in[17], (const float*)d_in[18], (const float*)d_in[19],
        (const float*)d_in[20], wb);
    cbprep_k<<<2, blk, 0, stream>>>(cb, cbh, cbl, sc);

    enc12_k<<<g16, blk, 0, stream>>>(x, enc_w1, enc_b1, wb + 0 * 65536, enc_b2, Bbf);
    encmid_k<<<g16, blk, 0, stream>>>(Bbf, wb + 1 * 65536, enc_b3,
        wb + 2 * 65536, wb + 3 * 65536, wb + 4 * 65536, wb + 5 * 65536, Abf);

    vqf_k<<<512, blk, 0, stream>>>(Abf, wb + 6 * 65536, pre_vq_b, cb,
                                   cbh, cbl, sc, Qbf, cnt, lsum);

    decmid_k<<<g16, blk, 0, stream>>>(Qbf, wb + 7 * 65536, dec_b1,
        wb + 8 * 65536, wb + 9 * 65536, wb + 10 * 65536, wb + 11 * 65536,
        wb + 12 * 65536, ct1_b, Bbf);

    ct2_k<<<dim3(8, 128), blk, 0, stream>>>(Bbf, ct2_w, ct2_b, out + 1);
    finalize_k<<<1, 512, 0, stream>>>(cnt, lsum, out, out_size);
}

// Round 9
// 357.579 us; speedup vs baseline: 1.1710x; 1.0027x over previous
//
#include <hip/hip_runtime.h>
#include <hip/hip_bf16.h>
#include <math.h>

using bf16 = __hip_bfloat16;
typedef __attribute__((ext_vector_type(4))) float f32x4;
typedef __attribute__((ext_vector_type(8))) short s16x8;

#define MFMA16(a,b,c) __builtin_amdgcn_mfma_f32_16x16x32_bf16((a),(b),(c),0,0,0)

// ---------------------------------------------------------------------------
// VQ-VAE forward. B=128, L=4096, H=128, RH=64, D=64, K=512.
// Channel-last bf16. Padded LDS rows (no XOR swizzle), aliased dead regions.
// Strides: 128ch rows -> 136 elems (272B), 64ch rows -> 72 elems (144B).
// ---------------------------------------------------------------------------

__device__ inline float bf2f(unsigned short u) {
    union { float f; unsigned v; } c; c.v = ((unsigned)u) << 16; return c.f;
}
__device__ inline unsigned short bfbits(float f) {
    union { bf16 h; unsigned short u; } c; c.h = __float2bfloat16(f); return c.u;
}
__device__ inline s16x8 relu8(s16x8 v) {
#pragma unroll
    for (int j = 0; j < 8; ++j)
        v[j] = (short)(((unsigned short)v[j] & 0x8000u) ? 0 : (unsigned short)v[j]);
    return v;
}

// ===========================================================================
// encmid: enc3 (128->128 K3) + res1 + res2 + final relu.  Bbf -> Abf.
// sY 80x136 bf16 @0 (21760B); sX 96x136 bf16 @21760 (26112B); sH 80x72 bf16
// aliases sX (dead after phase 1). Total 47872B -> 3 blocks/CU.
// ===========================================================================
__global__ __launch_bounds__(256, 3) void encmid_k(
    const bf16* __restrict__ in, const bf16* __restrict__ w3t,
    const float* __restrict__ b3, const bf16* __restrict__ r1w1,
    const bf16* __restrict__ r1w2, const bf16* __restrict__ r2w1,
    const bf16* __restrict__ r2w2, bf16* __restrict__ out)
{
    __shared__ __align__(16) char smem[47872];
    char* sY = smem;            // stride 272 B
    char* sX = smem + 21760;    // stride 272 B
    char* sH = smem + 21760;    // stride 144 B (aliases sX after phase 1)
    const int tid = threadIdx.x;
    const int b   = blockIdx.y;
    const int l0  = blockIdx.x * 64;
    const bf16* inb = in + (size_t)b * 1024 * 128;

    for (int i = tid; i < 96 * 16; i += 256) {
        int t = i >> 4, c0 = (i & 15) * 8;
        int g = l0 - 16 + t;
        s16x8 v = {};
        if (g >= 0 && g < 1024) v = *(const s16x8*)(inb + (size_t)g * 128 + c0);
        *(s16x8*)(sX + ((t * 136 + c0) << 1)) = v;
    }
    __syncthreads();

    const int lane = tid & 63;
    const int wid  = __builtin_amdgcn_readfirstlane(tid >> 6);
    const int lr   = lane & 15;
    const int kg   = lane >> 4;
    const f32x4 zf4 = {0.f, 0.f, 0.f, 0.f};

    // ---- phase 1: enc3 -> sY (80 rows x 128 co), bias, OOR-zero ----
    {
        const int co0 = wid * 32;
        f32x4 acc[2][5];
#pragma unroll
        for (int cf = 0; cf < 2; ++cf)
#pragma unroll
            for (int lf = 0; lf < 5; ++lf) acc[cf][lf] = zf4;
#pragma unroll
        for (int k = 0; k < 3; ++k) {
            const bf16* Ab = w3t + (size_t)k * 128 * 128;
#pragma unroll
            for (int ks = 0; ks < 4; ++ks) {
                s16x8 af[2];
#pragma unroll
                for (int cf = 0; cf < 2; ++cf)
                    af[cf] = *(const s16x8*)(Ab + (co0 + cf * 16 + lr) * 128 + ks * 32 + kg * 8);
                s16x8 bfr[5];
#pragma unroll
                for (int lf = 0; lf < 5; ++lf) {
                    int tx = lf * 16 + lr + 7 + k;
                    bfr[lf] = *(const s16x8*)(sX + ((tx * 136 + ks * 32 + kg * 8) << 1));
                }
#pragma unroll
                for (int cf = 0; cf < 2; ++cf)
#pragma unroll
                    for (int lf = 0; lf < 5; ++lf)
                        acc[cf][lf] = MFMA16(af[cf], bfr[lf], acc[cf][lf]);
            }
        }
        __syncthreads();   // sX reads done before sY writes race? (sY separate) -- keep for sH alias safety below
#pragma unroll
        for (int cf = 0; cf < 2; ++cf)
#pragma unroll
            for (int lf = 0; lf < 5; ++lf) {
                int row = lf * 16 + lr;
                int p   = l0 - 8 + row;
                int cb0 = co0 + cf * 16 + kg * 4;
                bool ok = (p >= 0 && p < 1024);
                float r[4];
#pragma unroll
                for (int j = 0; j < 4; ++j)
                    r[j] = ok ? (acc[cf][lf][j] + b3[cb0 + j]) : 0.f;
                uint2 pk;
                pk.x = (unsigned)bfbits(r[0]) | ((unsigned)bfbits(r[1]) << 16);
                pk.y = (unsigned)bfbits(r[2]) | ((unsigned)bfbits(r[3]) << 16);
                *(uint2*)(sY + ((row * 136 + cb0) << 1)) = pk;
            }
    }
    __syncthreads();

    // ---- phases 2..5: two res blocks ----
#pragma unroll 1
    for (int blk = 0; blk < 2; ++blk) {
        const bf16* w1 = blk ? r2w1 : r1w1;
        {
            const int co0 = wid * 16;
            f32x4 acc[5];
#pragma unroll
            for (int lf = 0; lf < 5; ++lf) acc[lf] = zf4;
#pragma unroll
            for (int k = 0; k < 3; ++k) {
                const bf16* Ab = w1 + (size_t)k * 64 * 128;
#pragma unroll
                for (int ks = 0; ks < 4; ++ks) {
                    s16x8 a = *(const s16x8*)(Ab + (co0 + lr) * 128 + ks * 32 + kg * 8);
                    s16x8 bfr[5];
#pragma unroll
                    for (int lf = 0; lf < 5; ++lf) {
                        int ry = lf * 16 + lr + k - 1;
                        ry = (ry < 0) ? 0 : (ry > 79 ? 79 : ry);
                        bfr[lf] = relu8(*(const s16x8*)(sY + ((ry * 136 + ks * 32 + kg * 8) << 1)));
                    }
#pragma unroll
                    for (int lf = 0; lf < 5; ++lf)
                        acc[lf] = MFMA16(a, bfr[lf], acc[lf]);
                }
            }
#pragma unroll
            for (int lf = 0; lf < 5; ++lf) {
                int row = lf * 16 + lr;
                int ch0 = co0 + kg * 4;
                uint2 pk;
                pk.x = (unsigned)bfbits(fmaxf(acc[lf][0], 0.f)) |
                       ((unsigned)bfbits(fmaxf(acc[lf][1], 0.f)) << 16);
                pk.y = (unsigned)bfbits(fmaxf(acc[lf][2], 0.f)) |
                       ((unsigned)bfbits(fmaxf(acc[lf][3], 0.f)) << 16);
                *(uint2*)(sH + ((row * 72 + ch0) << 1)) = pk;
            }
        }
        __syncthreads();

        if (blk == 0) {
            const int co0 = wid * 32;
            f32x4 acc[2][5];
#pragma unroll
            for (int cf = 0; cf < 2; ++cf)
#pragma unroll
                for (int lf = 0; lf < 5; ++lf) acc[cf][lf] = zf4;
#pragma unroll
            for (int ks = 0; ks < 2; ++ks) {
                s16x8 af[2];
#pragma unroll
                for (int cf = 0; cf < 2; ++cf)
                    af[cf] = *(const s16x8*)(r1w2 + (size_t)(co0 + cf * 16 + lr) * 64 + ks * 32 + kg * 8);
                s16x8 bfr[5];
#pragma unroll
                for (int lf = 0; lf < 5; ++lf) {
                    int row = lf * 16 + lr;
                    bfr[lf] = *(const s16x8*)(sH + ((row * 72 + ks * 32 + kg * 8) << 1));
                }
#pragma unroll
                for (int cf = 0; cf < 2; ++cf)
#pragma unroll
                    for (int lf = 0; lf < 5; ++lf)
                        acc[cf][lf] = MFMA16(af[cf], bfr[lf], acc[cf][lf]);
            }
#pragma unroll
            for (int cf = 0; cf < 2; ++cf)
#pragma unroll
                for (int lf = 0; lf < 5; ++lf) {
                    int row = lf * 16 + lr;
                    int p   = l0 - 8 + row;
                    int cb0 = co0 + cf * 16 + kg * 4;
                    uint2 old = *(const uint2*)(sY + ((row * 136 + cb0) << 1));
                    bool ok = (p >= 0 && p < 1024);
                    float r[4];
                    r[0] = acc[cf][lf][0] + bf2f((unsigned short)(old.x & 0xffff));
                    r[1] = acc[cf][lf][1] + bf2f((unsigned short)(old.x >> 16));
                    r[2] = acc[cf][lf][2] + bf2f((unsigned short)(old.y & 0xffff));
                    r[3] = acc[cf][lf][3] + bf2f((unsigned short)(old.y >> 16));
                    uint2 pk;
                    pk.x = ok ? ((unsigned)bfbits(r[0]) | ((unsigned)bfbits(r[1]) << 16)) : 0u;
                    pk.y = ok ? ((unsigned)bfbits(r[2]) | ((unsigned)bfbits(r[3]) << 16)) : 0u;
                    *(uint2*)(sY + ((row * 136 + cb0) << 1)) = pk;
                }
            __syncthreads();
        } else {
            const int co0 = wid * 32;
            f32x4 acc[2][4];
#pragma unroll
            for (int cf = 0; cf < 2; ++cf)
#pragma unroll
                for (int lf = 0; lf < 4; ++lf) acc[cf][lf] = zf4;
#pragma unroll
            for (int ks = 0; ks < 2; ++ks) {
                s16x8 af[2];
#pragma unroll
                for (int cf = 0; cf < 2; ++cf)
                    af[cf] = *(const s16x8*)(r2w2 + (size_t)(co0 + cf * 16 + lr) * 64 + ks * 32 + kg * 8);
                s16x8 bfr[4];
#pragma unroll
                for (int lf = 0; lf < 4; ++lf) {
                    int row = 8 + lf * 16 + lr;
                    bfr[lf] = *(const s16x8*)(sH + ((row * 72 + ks * 32 + kg * 8) << 1));
                }
#pragma unroll
                for (int cf = 0; cf < 2; ++cf)
#pragma unroll
                    for (int lf = 0; lf < 4; ++lf)
                        acc[cf][lf] = MFMA16(af[cf], bfr[lf], acc[cf][lf]);
            }
#pragma unroll
            for (int cf = 0; cf < 2; ++cf)
#pragma unroll
                for (int lf = 0; lf < 4; ++lf) {
                    int row = 8 + lf * 16 + lr;
                    int cb0 = co0 + cf * 16 + kg * 4;
                    uint2 old = *(const uint2*)(sY + ((row * 136 + cb0) << 1));
                    float r[4];
                    r[0] = fmaxf(acc[cf][lf][0] + bf2f((unsigned short)(old.x & 0xffff)), 0.f);
                    r[1] = fmaxf(acc[cf][lf][1] + bf2f((unsigned short)(old.x >> 16)), 0.f);
                    r[2] = fmaxf(acc[cf][lf][2] + bf2f((unsigned short)(old.y & 0xffff)), 0.f);
                    r[3] = fmaxf(acc[cf][lf][3] + bf2f((unsigned short)(old.y >> 16)), 0.f);
                    uint2 pk;
                    pk.x = (unsigned)bfbits(r[0]) | ((unsigned)bfbits(r[1]) << 16);
                    pk.y = (unsigned)bfbits(r[2]) | ((unsigned)bfbits(r[3]) << 16);
                    *(uint2*)(out + ((size_t)b * 1024 + l0 + lf * 16 + lr) * 128 + cb0) = pk;
                }
        }
    }
}

// ===========================================================================
// decmid: dec1 + res1 + res2(+relu) + ct1 convT.  Qbf -> (b,2048,64) bf16.
// sY 80x136 @0 (21760B); sQ 96x72 @21760 (13824B); sH 80x72 aliases sQ.
// Total 35584B -> 4 blocks/CU.
// ===========================================================================
__global__ __launch_bounds__(256, 4) void decmid_k(
    const bf16* __restrict__ qin, const bf16* __restrict__ dw1,
    const float* __restrict__ db1, const bf16* __restrict__ r1w1,
    const bf16* __restrict__ r1w2, const bf16* __restrict__ r2w1,
    const bf16* __restrict__ r2w2, const bf16* __restrict__ ct1w,
    const float* __restrict__ ct1b, bf16* __restrict__ out)
{
    __shared__ __align__(16) char smem[35584];
    char* sY = smem;            // stride 272 B
    char* sQ = smem + 21760;    // stride 144 B
    char* sH = smem + 21760;    // stride 144 B (aliases sQ after phase 1)
    const int tid = threadIdx.x;
    const int b   = blockIdx.y;
    const int l0  = blockIdx.x * 64;
    const bf16* inb = qin + (size_t)b * 1024 * 64;

    for (int i = tid; i < 96 * 8; i += 256) {
        int t = i >> 3, c0 = (i & 7) * 8;
        int g = l0 - 16 + t;
        s16x8 v = {};
        if (g >= 0 && g < 1024) v = *(const s16x8*)(inb + (size_t)g * 64 + c0);
        *(s16x8*)(sQ + ((t * 72 + c0) << 1)) = v;
    }
    __syncthreads();

    const int lane = tid & 63;
    const int wid  = __builtin_amdgcn_readfirstlane(tid >> 6);
    const int lr   = lane & 15;
    const int kg   = lane >> 4;
    const f32x4 zf4 = {0.f, 0.f, 0.f, 0.f};

    // ---- phase 1: dec1 -> sY, bias, OOR-zero ----
    {
        const int co0 = wid * 32;
        f32x4 acc[2][5];
#pragma unroll
        for (int cf = 0; cf < 2; ++cf)
#pragma unroll
            for (int lf = 0; lf < 5; ++lf) acc[cf][lf] = zf4;
#pragma unroll
        for (int k = 0; k < 3; ++k) {
            const bf16* Ab = dw1 + (size_t)k * 128 * 64;
#pragma unroll
            for (int ks = 0; ks < 2; ++ks) {
                s16x8 af[2];
#pragma unroll
                for (int cf = 0; cf < 2; ++cf)
                    af[cf] = *(const s16x8*)(Ab + (co0 + cf * 16 + lr) * 64 + ks * 32 + kg * 8);
                s16x8 bfr[5];
#pragma unroll
                for (int lf = 0; lf < 5; ++lf) {
                    int tx = lf * 16 + lr + 7 + k;
                    bfr[lf] = *(const s16x8*)(sQ + ((tx * 72 + ks * 32 + kg * 8) << 1));
                }
#pragma unroll
                for (int cf = 0; cf < 2; ++cf)
#pragma unroll
                    for (int lf = 0; lf < 5; ++lf)
                        acc[cf][lf] = MFMA16(af[cf], bfr[lf], acc[cf][lf]);
            }
        }
        __syncthreads();   // sQ reads complete before sH overwrites (alias)
#pragma unroll
        for (int cf = 0; cf < 2; ++cf)
#pragma unroll
            for (int lf = 0; lf < 5; ++lf) {
                int row = lf * 16 + lr;
                int p   = l0 - 8 + row;
                int cb0 = co0 + cf * 16 + kg * 4;
                bool ok = (p >= 0 && p < 1024);
                float r[4];
#pragma unroll
                for (int j = 0; j < 4; ++j)
                    r[j] = ok ? (acc[cf][lf][j] + db1[cb0 + j]) : 0.f;
                uint2 pk;
                pk.x = (unsigned)bfbits(r[0]) | ((unsigned)bfbits(r[1]) << 16);
                pk.y = (unsigned)bfbits(r[2]) | ((unsigned)bfbits(r[3]) << 16);
                *(uint2*)(sY + ((row * 136 + cb0) << 1)) = pk;
            }
    }
    __syncthreads();

    // ---- res blocks ----
#pragma unroll 1
    for (int blk = 0; blk < 2; ++blk) {
        const bf16* w1 = blk ? r2w1 : r1w1;
        const bf16* w2 = blk ? r2w2 : r1w2;
        {
            const int co0 = wid * 16;
            f32x4 acc[5];
#pragma unroll
            for (int lf = 0; lf < 5; ++lf) acc[lf] = zf4;
#pragma unroll
            for (int k = 0; k < 3; ++k) {
                const bf16* Ab = w1 + (size_t)k * 64 * 128;
#pragma unroll
                for (int ks = 0; ks < 4; ++ks) {
                    s16x8 a = *(const s16x8*)(Ab + (co0 + lr) * 128 + ks * 32 + kg * 8);
                    s16x8 bfr[5];
#pragma unroll
                    for (int lf = 0; lf < 5; ++lf) {
                        int ry = lf * 16 + lr + k - 1;
                        ry = (ry < 0) ? 0 : (ry > 79 ? 79 : ry);
                        bfr[lf] = relu8(*(const s16x8*)(sY + ((ry * 136 + ks * 32 + kg * 8) << 1)));
                    }
#pragma unroll
                    for (int lf = 0; lf < 5; ++lf)
                        acc[lf] = MFMA16(a, bfr[lf], acc[lf]);
                }
            }
#pragma unroll
            for (int lf = 0; lf < 5; ++lf) {
                int row = lf * 16 + lr;
                int ch0 = co0 + kg * 4;
                uint2 pk;
                pk.x = (unsigned)bfbits(fmaxf(acc[lf][0], 0.f)) |
                       ((unsigned)bfbits(fmaxf(acc[lf][1], 0.f)) << 16);
                pk.y = (unsigned)bfbits(fmaxf(acc[lf][2], 0.f)) |
                       ((unsigned)bfbits(fmaxf(acc[lf][3], 0.f)) << 16);
                *(uint2*)(sH + ((row * 72 + ch0) << 1)) = pk;
            }
        }
        __syncthreads();
        {
            const int co0 = wid * 32;
            f32x4 acc[2][5];
#pragma unroll
            for (int cf = 0; cf < 2; ++cf)
#pragma unroll
                for (int lf = 0; lf < 5; ++lf) acc[cf][lf] = zf4;
#pragma unroll
            for (int ks = 0; ks < 2; ++ks) {
                s16x8 af[2];
#pragma unroll
                for (int cf = 0; cf < 2; ++cf)
                    af[cf] = *(const s16x8*)(w2 + (size_t)(co0 + cf * 16 + lr) * 64 + ks * 32 + kg * 8);
                s16x8 bfr[5];
#pragma unroll
                for (int lf = 0; lf < 5; ++lf) {
                    int row = lf * 16 + lr;
                    bfr[lf] = *(const s16x8*)(sH + ((row * 72 + ks * 32 + kg * 8) << 1));
                }
#pragma unroll
                for (int cf = 0; cf < 2; ++cf)
#pragma unroll
                    for (int lf = 0; lf < 5; ++lf)
                        acc[cf][lf] = MFMA16(af[cf], bfr[lf], acc[cf][lf]);
            }
#pragma unroll
            for (int cf = 0; cf < 2; ++cf)
#pragma unroll
                for (int lf = 0; lf < 5; ++lf) {
                    int row = lf * 16 + lr;
                    int p   = l0 - 8 + row;
                    int cb0 = co0 + cf * 16 + kg * 4;
                    uint2 old = *(const uint2*)(sY + ((row * 136 + cb0) << 1));
                    bool ok = (p >= 0 && p < 1024);
                    float r[4];
                    r[0] = acc[cf][lf][0] + bf2f((unsigned short)(old.x & 0xffff));
                    r[1] = acc[cf][lf][1] + bf2f((unsigned short)(old.x >> 16));
                    r[2] = acc[cf][lf][2] + bf2f((unsigned short)(old.y & 0xffff));
                    r[3] = acc[cf][lf][3] + bf2f((unsigned short)(old.y >> 16));
                    if (blk == 1)
#pragma unroll
                        for (int j = 0; j < 4; ++j) r[j] = fmaxf(r[j], 0.f);
                    uint2 pk;
                    pk.x = ok ? ((unsigned)bfbits(r[0]) | ((unsigned)bfbits(r[1]) << 16)) : 0u;
                    pk.y = ok ? ((unsigned)bfbits(r[2]) | ((unsigned)bfbits(r[3]) << 16)) : 0u;
                    *(uint2*)(sY + ((row * 136 + cb0) << 1)) = pk;
                }
        }
        __syncthreads();
    }

    // ---- phase 6: ct1 convT -> global (b,2048,64) ----
    {
        const int co0 = (wid & 1) * 32;
        const int mh  = wid >> 1;
        f32x4 acc[2][2][2];
#pragma unroll
        for (int g = 0; g < 2; ++g)
#pragma unroll
            for (int cf = 0; cf < 2; ++cf)
#pragma unroll
                for (int j = 0; j < 2; ++j) acc[g][cf][j] = zf4;
#pragma unroll
        for (int g = 0; g < 2; ++g)
#pragma unroll
            for (int k = 0; k < 2; ++k) {
                const bf16* Ab = ct1w + (size_t)(g * 2 + k) * 64 * 128;
                const int doff = (g == 0) ? (k - 1) : k;
#pragma unroll
                for (int ks = 0; ks < 4; ++ks) {
                    s16x8 af[2];
#pragma unroll
                    for (int cf = 0; cf < 2; ++cf)
                        af[cf] = *(const s16x8*)(Ab + (co0 + cf * 16 + lr) * 128 + ks * 32 + kg * 8);
                    s16x8 bfr[2];
#pragma unroll
                    for (int j = 0; j < 2; ++j) {
                        int ty = 8 + (mh * 2 + j) * 16 + lr + doff;
                        bfr[j] = *(const s16x8*)(sY + ((ty * 136 + ks * 32 + kg * 8) << 1));
                    }
#pragma unroll
                    for (int cf = 0; cf < 2; ++cf)
#pragma unroll
                        for (int j = 0; j < 2; ++j)
                            acc[g][cf][j] = MFMA16(af[cf], bfr[j], acc[g][cf][j]);
                }
            }
#pragma unroll
        for (int g = 0; g < 2; ++g)
#pragma unroll
            for (int cf = 0; cf < 2; ++cf)
#pragma unroll
                for (int j = 0; j < 2; ++j) {
                    int m   = (mh * 2 + j) * 16 + lr;
                    int cb0 = co0 + cf * 16 + kg * 4;
                    float r[4];
#pragma unroll
                    for (int jj = 0; jj < 4; ++jj)
                        r[jj] = fmaxf(acc[g][cf][j][jj] + ct1b[cb0 + jj], 0.f);
                    uint2 pk;
                    pk.x = (unsigned)bfbits(r[0]) | ((unsigned)bfbits(r[1]) << 16);
                    pk.y = (unsigned)bfbits(r[2]) | ((unsigned)bfbits(r[3]) << 16);
                    *(uint2*)(out + ((size_t)b * 2048 + 2 * (l0 + m) + g) * 64 + cb0) = pk;
                }
    }
}

// Fused enc1+enc2: x fp32 -> h1 (LDS, stride 72) -> enc2 GEMM -> bf16 relu.
__global__ __launch_bounds__(256) void enc12_k(
    const float* __restrict__ x, const float* __restrict__ w1,
    const float* __restrict__ b1, const bf16* __restrict__ w2t,
    const float* __restrict__ b2, bf16* __restrict__ out)
{
    __shared__ float sXf[268];
    __shared__ float sW1[256];
    __shared__ float sB1[64];
    __shared__ __align__(16) char sX[132 * 144];
    const int tid = threadIdx.x;
    const int b   = blockIdx.y;
    const int l0  = blockIdx.x * 64;
    const float* xb = x + (size_t)b * 4096;

    for (int i = tid; i < 266; i += 256) {
        int g = 4 * l0 - 3 + i;
        sXf[i] = (g >= 0 && g < 4096) ? xb[g] : 0.f;
    }
    if (tid < 256) sW1[tid] = w1[tid];
    if (tid < 64)  sB1[tid] = b1[tid];
    __syncthreads();

    for (int i = tid; i < 132 * 64; i += 256) {
        int t = i >> 6, c = i & 63;
        int p = (t < 66) ? 2 * (l0 + t) : 2 * (l0 + t - 66) - 1;
        float v = 0.f;
        if (p >= 0 && p < 2048) {
            int xi = 2 * p - 4 * l0 + 2;
            float a = sB1[c];
#pragma unroll
            for (int k = 0; k < 4; ++k) a = fmaf(sXf[xi + k], sW1[c * 4 + k], a);
            v = fmaxf(a, 0.f);
        }
        *(bf16*)(sX + ((t * 72 + c) << 1)) = __float2bfloat16(v);
    }
    __syncthreads();

    const int lane = tid & 63;
    const int wid  = __builtin_amdgcn_readfirstlane(tid >> 6);
    const int co0  = wid * 32;
    const int lr   = lane & 15;
    const int kg   = lane >> 4;

    f32x4 acc[2][4];
#pragma unroll
    for (int cf = 0; cf < 2; ++cf)
#pragma unroll
        for (int lf = 0; lf < 4; ++lf) acc[cf][lf] = (f32x4){0.f, 0.f, 0.f, 0.f};

#pragma unroll
    for (int k = 0; k < 4; ++k) {
        const int roff = (k == 0) ? 66 : (k == 1) ? 0 : (k == 2) ? 67 : 1;
        const bf16* Ab = w2t + (size_t)k * 128 * 64;
#pragma unroll
        for (int ks = 0; ks < 2; ++ks) {
            s16x8 af[2];
#pragma unroll
            for (int cf = 0; cf < 2; ++cf)
                af[cf] = *(const s16x8*)(Ab + (co0 + cf * 16 + lr) * 64 + ks * 32 + kg * 8);
            s16x8 bfr[4];
#pragma unroll
            for (int lf = 0; lf < 4; ++lf) {
                int t = roff + lf * 16 + lr;
                bfr[lf] = *(const s16x8*)(sX + ((t * 72 + ks * 32 + kg * 8) << 1));
            }
#pragma unroll
            for (int cf = 0; cf < 2; ++cf)
#pragma unroll
                for (int lf = 0; lf < 4; ++lf)
                    acc[cf][lf] = MFMA16(af[cf], bfr[lf], acc[cf][lf]);
        }
    }

#pragma unroll
    for (int cf = 0; cf < 2; ++cf)
#pragma unroll
        for (int lf = 0; lf < 4; ++lf) {
            int cb0  = co0 + cf * 16 + kg * 4;
            int lcol = lf * 16 + lr;
            float r[4];
#pragma unroll
            for (int j = 0; j < 4; ++j)
                r[j] = fmaxf(acc[cf][lf][j] + b2[cb0 + j], 0.f);
            uint2 pk;
            pk.x = (unsigned)bfbits(r[0]) | ((unsigned)bfbits(r[1]) << 16);
            pk.y = (unsigned)bfbits(r[2]) | ((unsigned)bfbits(r[3]) << 16);
            *(uint2*)(out + ((size_t)b * 1024 + l0 + lcol) * 128 + cb0) = pk;
        }
}

// Final convT: 64->1 ch, x2 upsample; fp32 out. Stride-72 padded LDS.
__global__ __launch_bounds__(256) void ct2_k(
    const bf16* __restrict__ in, const float* __restrict__ w,
    const float* __restrict__ bias, float* __restrict__ out)
{
    __shared__ __align__(16) char sX[258 * 144];
    const int tid = threadIdx.x;
    const int b   = blockIdx.y;
    const int m0  = blockIdx.x * 256;
    const bf16* inb = in + (size_t)b * 2048 * 64;
    for (int i = tid; i < 258 * 8; i += 256) {
        int t = i >> 3, c0 = (i & 7) * 8;
        int g = m0 - 1 + t;
        s16x8 v = {};
        if (g >= 0 && g < 2048) v = *(const s16x8*)(inb + (size_t)g * 64 + c0);
        *(s16x8*)(sX + ((t * 72 + c0) << 1)) = v;
    }
    __syncthreads();
    float e = bias[0], o = bias[0];
#pragma unroll
    for (int c0 = 0; c0 < 64; c0 += 8) {
        s16x8 vm1 = *(const s16x8*)(sX + (((tid + 0) * 72 + c0) << 1));
        s16x8 v0  = *(const s16x8*)(sX + (((tid + 1) * 72 + c0) << 1));
        s16x8 vp1 = *(const s16x8*)(sX + (((tid + 2) * 72 + c0) << 1));
#pragma unroll
        for (int j = 0; j < 8; ++j) {
            int ci = c0 + j;
            float xm1 = bf2f((unsigned short)vm1[j]);
            float x0  = bf2f((unsigned short)v0[j]);
            float xp1 = bf2f((unsigned short)vp1[j]);
            e = fmaf(x0,  w[ci * 4 + 1], fmaf(xm1, w[ci * 4 + 3], e));
            o = fmaf(xp1, w[ci * 4 + 0], fmaf(x0,  w[ci * 4 + 2], o));
        }
    }
    int m = m0 + tid;
    out[(size_t)b * 4096 + 2 * m]     = e;
    out[(size_t)b * 4096 + 2 * m + 1] = o;
}

// Weight transform: fp32 conv weights -> bf16 [tap][co][ci] matrices.
__global__ __launch_bounds__(256) void wx_k(
    const float* ew2, const float* ew3, const float* er1a, const float* er1b,
    const float* er2a, const float* er2b, const float* pvw, const float* dw1,
    const float* dr1a, const float* dr1b, const float* dr2a, const float* dr2b,
    const float* ct1w, bf16* wb)
{
    const int job = blockIdx.x;
    bf16* dst = wb + (size_t)job * 65536;
    const float* src; int CO, CI, K;
    switch (job) {
        case 0:  src = ew2;  CO = 128; CI = 64;  K = 4; break;
        case 1:  src = ew3;  CO = 128; CI = 128; K = 3; break;
        case 2:  src = er1a; CO = 64;  CI = 128; K = 3; break;
        case 3:  src = er1b; CO = 128; CI = 64;  K = 1; break;
        case 4:  src = er2a; CO = 64;  CI = 128; K = 3; break;
        case 5:  src = er2b; CO = 128; CI = 64;  K = 1; break;
        case 6:  src = pvw;  CO = 64;  CI = 128; K = 1; break;
        case 7:  src = dw1;  CO = 128; CI = 64;  K = 3; break;
        case 8:  src = dr1a; CO = 64;  CI = 128; K = 3; break;
        case 9:  src = dr1b; CO = 128; CI = 64;  K = 1; break;
        case 10: src = dr2a; CO = 64;  CI = 128; K = 3; break;
        case 11: src = dr2b; CO = 128; CI = 64;  K = 1; break;
        default: src = ct1w; CO = 64;  CI = 128; K = 4; break;
    }
    const int tot = CO * CI * K;
    for (int i = blockIdx.y * 256 + threadIdx.x; i < tot; i += gridDim.y * 256) {
        if (job < 12) {
            int k = i / (CO * CI); int r = i - k * CO * CI;
            int co = r / CI; int ci = r - co * CI;
            dst[i] = __float2bfloat16(src[((size_t)co * CI + ci) * K + k]);
        } else {
            const int TAP[4] = {3, 1, 2, 0};
            int g = i / (64 * 128); int r = i - g * 64 * 128;
            int co = r / 128; int ci = r - co * 128;
            dst[i] = __float2bfloat16(src[((size_t)ci * 64 + co) * 4 + TAP[g]]);
        }
    }
}

// codebook prep: fp32 norms + hi/lo bf16 split
__global__ __launch_bounds__(256) void cbprep_k(
    const float* __restrict__ cb, bf16* __restrict__ cbh, bf16* __restrict__ cbl,
    float* __restrict__ sc)
{
    int k = blockIdx.x * 256 + threadIdx.x;
    const float* c = cb + (size_t)k * 64;
    float s = 0.f;
#pragma unroll
    for (int d = 0; d < 64; ++d) s = fmaf(c[d], c[d], s);
    sc[k] = s;
#pragma unroll
    for (int c0 = 0; c0 < 64; c0 += 8) {
        union { unsigned short u[8]; s16x8 v; } ph, pl;
#pragma unroll
        for (int j = 0; j < 8; ++j) {
            float v = c[c0 + j];
            unsigned short h = bfbits(v);
            ph.u[j] = h;
            pl.u[j] = bfbits(v - bf2f(h));
        }
        *(s16x8*)(cbh + (size_t)k * 64 + c0) = ph.v;
        *(s16x8*)(cbl + (size_t)k * 64 + c0) = pl.v;
    }
}

// Fused pre_vq + VQ. 1024 blocks x 128 positions. A tile / z tile alias.
__global__ __launch_bounds__(256, 4) void vqf_k(
    const bf16* __restrict__ A, const bf16* __restrict__ pvw,
    const float* __restrict__ pvb, const float* __restrict__ cbf,
    const bf16* __restrict__ cbh, const bf16* __restrict__ cbl,
    const float* __restrict__ sc, bf16* __restrict__ q,
    float* __restrict__ counts, float* __restrict__ loss_sum)
{
    __shared__ __align__(16) char sMem[34816];   // A 128x136 bf16 | z 128x68 f32
    __shared__ float sSC[512];
    __shared__ float sHist[512];
    __shared__ int   sBK[128];
    __shared__ float sWS[4];
    const int tid = threadIdx.x;
    sSC[tid] = sc[tid]; sSC[tid + 256] = sc[tid + 256];
    sHist[tid] = 0.f;   sHist[tid + 256] = 0.f;

    const int n0 = blockIdx.x * 128;
    for (int i = tid; i < 128 * 16; i += 256) {
        int t = i >> 4, c0 = (i & 15) * 8;
        s16x8 v = *(const s16x8*)(A + (size_t)(n0 + t) * 128 + c0);
        *(s16x8*)(sMem + ((t * 136 + c0) << 1)) = v;
    }
    __syncthreads();

    const int lane = tid & 63, wid = tid >> 6;
    const int lr = lane & 15, kg = lane >> 4;
    const int pw0 = wid * 32;
    const f32x4 zf4 = {0.f, 0.f, 0.f, 0.f};

    f32x4 zacc[4][2];
#pragma unroll
    for (int cf = 0; cf < 4; ++cf)
#pragma unroll
        for (int lf = 0; lf < 2; ++lf) zacc[cf][lf] = zf4;
#pragma unroll
    for (int ks = 0; ks < 4; ++ks) {
        s16x8 af[4];
#pragma unroll
        for (int cf = 0; cf < 4; ++cf)
            af[cf] = *(const s16x8*)(pvw + (size_t)(cf * 16 + lr) * 128 + ks * 32 + kg * 8);
        s16x8 bfr[2];
#pragma unroll
        for (int lf = 0; lf < 2; ++lf) {
            int t = pw0 + lf * 16 + lr;
            bfr[lf] = *(const s16x8*)(sMem + ((t * 136 + ks * 32 + kg * 8) << 1));
        }
#pragma unroll
        for (int cf = 0; cf < 4; ++cf)
#pragma unroll
            for (int lf = 0; lf < 2; ++lf)
                zacc[cf][lf] = MFMA16(af[cf], bfr[lf], zacc[cf][lf]);
    }
    __syncthreads();      // A reads done; region becomes z fp32 tile

#pragma unroll
    for (int cf = 0; cf < 4; ++cf)
#pragma unroll
        for (int lf = 0; lf < 2; ++lf) {
            int pos = pw0 + lf * 16 + lr;
            int ch  = cf * 16 + kg * 4;
            float4 v = make_float4(zacc[cf][lf][0] + pvb[ch],
                                   zacc[cf][lf][1] + pvb[ch + 1],
                                   zacc[cf][lf][2] + pvb[ch + 2],
                                   zacc[cf][lf][3] + pvb[ch + 3]);
            *(float4*)(sMem + (pos * 68 + ch) * 4) = v;
        }
    __syncthreads();

    s16x8 bh[2][2], bl[2][2];
#pragma unroll
    for (int lf = 0; lf < 2; ++lf)
#pragma unroll
        for (int ks = 0; ks < 2; ++ks) {
            int t = pw0 + lf * 16 + lr;
            int ch = ks * 32 + kg * 8;
            float4 v0 = *(const float4*)(sMem + (t * 68 + ch) * 4);
            float4 v1 = *(const float4*)(sMem + (t * 68 + ch) * 4 + 16);
            float v[8] = {v0.x, v0.y, v0.z, v0.w, v1.x, v1.y, v1.z, v1.w};
            union { unsigned short u[8]; s16x8 s; } ph, pl;
#pragma unroll
            for (int j = 0; j < 8; ++j) {
                unsigned short h = bfbits(v[j]);
                ph.u[j] = h;
                pl.u[j] = bfbits(v[j] - bf2f(h));
            }
            bh[lf][ks] = ph.s; bl[lf][ks] = pl.s;
        }

    float bestd[2] = {3.4e38f, 3.4e38f};
    int   bestk[2] = {0, 0};
#pragma unroll 2
    for (int cf = 0; cf < 32; ++cf) {
        int code = cf * 16 + lr;
        const bf16* ph = cbh + code * 64 + kg * 8;
        const bf16* pl = cbl + code * 64 + kg * 8;
        s16x8 ah0 = *(const s16x8*)ph;
        s16x8 ah1 = *(const s16x8*)(ph + 32);
        s16x8 al0 = *(const s16x8*)pl;
        s16x8 al1 = *(const s16x8*)(pl + 32);
        float s0 = sSC[cf * 16 + kg * 4 + 0];
        float s1 = sSC[cf * 16 + kg * 4 + 1];
        float s2 = sSC[cf * 16 + kg * 4 + 2];
        float s3 = sSC[cf * 16 + kg * 4 + 3];
        int kb = cf * 16 + kg * 4;
#pragma unroll
        for (int lf = 0; lf < 2; ++lf) {
            f32x4 acc = MFMA16(ah0, bh[lf][0], zf4);
            acc = MFMA16(ah1, bh[lf][1], acc);
            acc = MFMA16(al0, bh[lf][0], acc);
            acc = MFMA16(al1, bh[lf][1], acc);
            acc = MFMA16(ah0, bl[lf][0], acc);
            acc = MFMA16(ah1, bl[lf][1], acc);
            float d0 = fmaf(acc[0], -2.f, s0);
            float d1 = fmaf(acc[1], -2.f, s1);
            float d2 = fmaf(acc[2], -2.f, s2);
            float d3 = fmaf(acc[3], -2.f, s3);
            if (d0 < bestd[lf]) { bestd[lf] = d0; bestk[lf] = kb; }
            if (d1 < bestd[lf]) { bestd[lf] = d1; bestk[lf] = kb + 1; }
            if (d2 < bestd[lf]) { bestd[lf] = d2; bestk[lf] = kb + 2; }
            if (d3 < bestd[lf]) { bestd[lf] = d3; bestk[lf] = kb + 3; }
        }
    }
#pragma unroll
    for (int lf = 0; lf < 2; ++lf) {
#pragma unroll
        for (int off = 16; off <= 32; off <<= 1) {
            float od = __shfl_xor(bestd[lf], off, 64);
            int   ok = __shfl_xor(bestk[lf], off, 64);
            if (od < bestd[lf] || (od == bestd[lf] && ok < bestk[lf])) {
                bestd[lf] = od; bestk[lf] = ok;
            }
        }
        if (kg == 0) sBK[pw0 + lf * 16 + lr] = bestk[lf];
    }
    __syncthreads();

    // phase 2: pos = tid>>1, channel-half = (tid&1)*32
    const int pos  = tid >> 1;
    const int half = tid & 1;
    const int k = sBK[pos];
    if (half == 0) atomicAdd(&sHist[k], 1.f);
    float lsum = 0.f;
    const float* qp = cbf + (size_t)k * 64 + half * 32;
    bf16* qo = q + (size_t)(n0 + pos) * 64 + half * 32;
#pragma unroll
    for (int c0 = 0; c0 < 32; c0 += 8) {
        int zb = (pos * 68 + half * 32 + c0) * 4;
        float4 z0 = *(const float4*)(sMem + zb);
        float4 z1 = *(const float4*)(sMem + zb + 16);
        float4 q0 = *(const float4*)(qp + c0);
        float4 q1 = *(const float4*)(qp + c0 + 4);
        float qv[8] = {q0.x, q0.y, q0.z, q0.w, q1.x, q1.y, q1.z, q1.w};
        float zv[8] = {z0.x, z0.y, z0.z, z0.w, z1.x, z1.y, z1.z, z1.w};
        union { unsigned short u[8]; s16x8 v; } pk;
#pragma unroll
        for (int j = 0; j < 8; ++j) {
            float d = qv[j] - zv[j];
            lsum = fmaf(d, d, lsum);
            pk.u[j] = bfbits(qv[j]);
        }
        *(s16x8*)(qo + c0) = pk.v;
    }
#pragma unroll
    for (int off = 32; off > 0; off >>= 1) lsum += __shfl_down(lsum, off, 64);
    if ((tid & 63) == 0) sWS[tid >> 6] = lsum;
    __syncthreads();
    if (tid == 0) atomicAdd(loss_sum, sWS[0] + sWS[1] + sWS[2] + sWS[3]);
    float c0v = sHist[tid];       if (c0v != 0.f) atomicAdd(&counts[tid], c0v);
    float c1v = sHist[tid + 256]; if (c1v != 0.f) atomicAdd(&counts[tid + 256], c1v);
}

__global__ __launch_bounds__(512) void finalize_k(
    const float* __restrict__ counts, const float* __restrict__ loss_sum,
    float* __restrict__ d_out, int out_size)
{
    __shared__ float ws2[8];
    const int tid = threadIdx.x;
    float p = counts[tid] * (1.f / 131072.f);
    float e = p * logf(p + 1e-10f);
#pragma unroll
    for (int off = 32; off > 0; off >>= 1) e += __shfl_down(e, off, 64);
    const int lane = tid & 63, wid = tid >> 6;
    if (lane == 0) ws2[wid] = e;
    __syncthreads();
    if (tid == 0) {
        float s = 0.f;
        for (int i = 0; i < 8; ++i) s += ws2[i];
        d_out[0] = 1.25f * loss_sum[0] * (1.f / 8388608.f);  // (1+BETA)*mean
        d_out[out_size - 1] = expf(-s);
    }
}

extern "C" void kernel_launch(void* const* d_in, const int* in_sizes, int n_in,
                              void* d_out, int out_size, void* d_ws, size_t ws_size,
                              hipStream_t stream)
{
    const float* x        = (const float*)d_in[0];
    const float* enc_w1   = (const float*)d_in[1];
    const float* enc_b1   = (const float*)d_in[2];
    const float* enc_b2   = (const float*)d_in[4];
    const float* enc_b3   = (const float*)d_in[6];
    const float* pre_vq_b = (const float*)d_in[12];
    const float* cb       = (const float*)d_in[13];
    const float* dec_b1   = (const float*)d_in[15];
    const float* ct1_b    = (const float*)d_in[21];
    const float* ct2_w    = (const float*)d_in[22];
    const float* ct2_b    = (const float*)d_in[23];
    float* out = (float*)d_out;

    char* base = (char*)d_ws;
    bf16*  wb   = (bf16*)base;                            // 13 x 64K bf16
    bf16*  Abf  = (bf16*)(base + ((size_t)2   << 20));
    bf16*  Bbf  = (bf16*)(base + ((size_t)40  << 20));
    bf16*  Qbf  = (bf16*)(base + ((size_t)78  << 20));
    bf16*  cbh  = (bf16*)(base + ((size_t)96  << 20));
    bf16*  cbl  = (bf16*)(base + ((size_t)96  << 20) + 65536);
    float* sc   = (float*)(base + ((size_t)96  << 20) + 131072);
    float* cnt  = sc + 512;
    float* lsum = cnt + 512;

    (void)hipMemsetAsync(cnt, 0, 513 * sizeof(float), stream);

    dim3 blk(256);
    dim3 g16(16, 128);

    wx_k<<<dim3(13, 8), blk, 0, stream>>>(
        (const float*)d_in[3], (const float*)d_in[5], (const float*)d_in[7],
        (const float*)d_in[8], (const float*)d_in[9], (const float*)d_in[10],
        (const float*)d_in[11], (const float*)d_in[14], (const float*)d_in[16],
        (const float*)d_in[17], (const float*)d_in[18], (const float*)d_in[19],
        (const float*)d_in[20], wb);
    cbprep_k<<<2, blk, 0, stream>>>(cb, cbh, cbl, sc);

    enc12_k<<<g16, blk, 0, stream>>>(x, enc_w1, enc_b1, wb + 0 * 65536, enc_b2, Bbf);
    encmid_k<<<g16, blk, 0, stream>>>(Bbf, wb + 1 * 65536, enc_b3,
        wb + 2 * 65536, wb + 3 * 65536, wb + 4 * 65536, wb + 5 * 65536, Abf);

    vqf_k<<<1024, blk, 0, stream>>>(Abf, wb + 6 * 65536, pre_vq_b, cb,
                                    cbh, cbl, sc, Qbf, cnt, lsum);

    decmid_k<<<g16, blk, 0, stream>>>(Qbf, wb + 7 * 65536, dec_b1,
        wb + 8 * 65536, wb + 9 * 65536, wb + 10 * 65536, wb + 11 * 65536,
        wb + 12 * 65536, ct1_b, Bbf);

    ct2_k<<<dim3(8, 128), blk, 0, stream>>>(Bbf, ct2_w, ct2_b, out + 1);
    finalize_k<<<1, 512, 0, stream>>>(cnt, lsum, out, out_size);
}